// Round 2
// 1855.675 us; speedup vs baseline: 2.2048x; 2.2048x over previous
//
#include <hip/hip_runtime.h>
#include <math.h>

#define BB 4
#define LL 4096
#define DD 1024
#define HH 4
#define DKk 256
#define DVv 256
#define HIDD 512
#define NC 128   // number of 32-chunks in L

typedef unsigned short ushort_t;
typedef __attribute__((ext_vector_type(8))) short short8;
typedef __attribute__((ext_vector_type(4))) float floatx4;

__device__ __forceinline__ float sigm(float x) { return 1.f / (1.f + __expf(-x)); }

__device__ __forceinline__ float bf2f(ushort_t u) {
  union { unsigned int i; float f; } c; c.i = ((unsigned int)u) << 16; return c.f;
}
__device__ __forceinline__ ushort_t f2bf(float f) {
  union { float f; unsigned int i; } c; c.f = f;
  unsigned int lsb = (c.i >> 16) & 1u;
  return (ushort_t)((c.i + 0x7fffu + lsb) >> 16);
}
__device__ __forceinline__ void unpack2(unsigned int u, float& a, float& b) {
  union { unsigned int i; float f; } c0, c1;
  c0.i = u << 16; c1.i = u & 0xffff0000u; a = c0.f; b = c1.f;
}
__device__ __forceinline__ unsigned int pack2(float a, float b) {
  return (unsigned int)f2bf(a) | ((unsigned int)f2bf(b) << 16);
}
__device__ __forceinline__ void unpack8(const uint4 v, float* o) {
  unpack2(v.x, o[0], o[1]); unpack2(v.y, o[2], o[3]);
  unpack2(v.z, o[4], o[5]); unpack2(v.w, o[6], o[7]);
}

// ---- MFMA GEMM: C(M,N)=A(M,K)@W(N,K)^T. W fp32; A fp32 or bf16 (ABF16). ----
// BF16OUT: C stored bf16 else fp32.  ACT==1: +bias then SiLU.
template<int ACT, int BF16OUT, int ABF16>
__global__ __launch_bounds__(256) void gemm_mfma(const void* __restrict__ Av,
    const float* __restrict__ W, const float* __restrict__ bias,
    void* __restrict__ Cv, int M, int N, int K)
{
  __shared__ ushort_t As[128*32];
  __shared__ ushort_t Ws[128*32];
  const int tid = threadIdx.x;
  const int bm = blockIdx.y * 128, bn = blockIdx.x * 128;
  const int lane = tid & 63, wave = tid >> 6;
  const int wm = (wave >> 1) * 64, wn = (wave & 1) * 64;
  const int fr = lane & 15, fq = lane >> 4;     // frag row / k-quad
  const int sr = tid >> 1, kh = (tid & 1) * 16; // staging: row, k-half
  floatx4 acc[4][4];
#pragma unroll
  for (int i = 0; i < 4; ++i)
#pragma unroll
    for (int j = 0; j < 4; ++j) acc[i][j] = (floatx4){0.f, 0.f, 0.f, 0.f};

  for (int k0 = 0; k0 < K; k0 += 32) {
    uint4 pa0, pa1, pw0, pw1;
    if (ABF16) {
      const ushort_t* Ap = (const ushort_t*)Av + (size_t)(bm + sr) * K + k0 + kh;
      pa0 = *(const uint4*)(Ap);
      pa1 = *(const uint4*)(Ap + 8);
    } else {
      const float* Ap = (const float*)Av + (size_t)(bm + sr) * K + k0 + kh;
      const float4 a0 = *(const float4*)(Ap);     const float4 a1 = *(const float4*)(Ap + 4);
      const float4 a2 = *(const float4*)(Ap + 8); const float4 a3 = *(const float4*)(Ap + 12);
      pa0.x = pack2(a0.x, a0.y); pa0.y = pack2(a0.z, a0.w);
      pa0.z = pack2(a1.x, a1.y); pa0.w = pack2(a1.z, a1.w);
      pa1.x = pack2(a2.x, a2.y); pa1.y = pack2(a2.z, a2.w);
      pa1.z = pack2(a3.x, a3.y); pa1.w = pack2(a3.z, a3.w);
    }
    {
      const float* Wp = W + (size_t)(bn + sr) * K + k0 + kh;
      const float4 w0 = *(const float4*)(Wp);     const float4 w1 = *(const float4*)(Wp + 4);
      const float4 w2 = *(const float4*)(Wp + 8); const float4 w3 = *(const float4*)(Wp + 12);
      pw0.x = pack2(w0.x, w0.y); pw0.y = pack2(w0.z, w0.w);
      pw0.z = pack2(w1.x, w1.y); pw0.w = pack2(w1.z, w1.w);
      pw1.x = pack2(w2.x, w2.y); pw1.y = pack2(w2.z, w2.w);
      pw1.z = pack2(w3.x, w3.y); pw1.w = pack2(w3.z, w3.w);
    }
    __syncthreads();
    *(uint4*)&As[sr*32 + kh]     = pa0;
    *(uint4*)&As[sr*32 + kh + 8] = pa1;
    *(uint4*)&Ws[sr*32 + kh]     = pw0;
    *(uint4*)&Ws[sr*32 + kh + 8] = pw1;
    __syncthreads();
    short8 af[4], bf_[4];
#pragma unroll
    for (int mt = 0; mt < 4; ++mt)
      af[mt] = *(const short8*)&As[(wm + mt*16 + fr)*32 + fq*8];
#pragma unroll
    for (int nt = 0; nt < 4; ++nt)
      bf_[nt] = *(const short8*)&Ws[(wn + nt*16 + fr)*32 + fq*8];
#pragma unroll
    for (int mt = 0; mt < 4; ++mt)
#pragma unroll
      for (int nt = 0; nt < 4; ++nt)
        acc[mt][nt] = __builtin_amdgcn_mfma_f32_16x16x32_bf16(af[mt], bf_[nt], acc[mt][nt], 0, 0, 0);
  }
#pragma unroll
  for (int mt = 0; mt < 4; ++mt) {
#pragma unroll
    for (int reg = 0; reg < 4; ++reg) {
      const int row = bm + wm + mt*16 + fq*4 + reg;
#pragma unroll
      for (int nt = 0; nt < 4; ++nt) {
        const int col = bn + wn + nt*16 + fr;
        float v = acc[mt][nt][reg];
        if (ACT == 1) { v += bias[col]; v = v * sigm(v); }
        if (BF16OUT) ((ushort_t*)Cv)[(size_t)row * N + col] = f2bf(v);
        else         ((float*)Cv)[(size_t)row * N + col] = v;
      }
    }
  }
}

// ---- depthwise causal conv(k=4)+SiLU, bf16 in/out, relayout to (B,H,L,DK) --
__global__ __launch_bounds__(256) void conv_silu_kernel(const ushort_t* __restrict__ xin,
    const float* __restrict__ wc, ushort_t* __restrict__ outp)
{
  const size_t idx = (size_t)blockIdx.x * 256 + threadIdx.x;  // over B*L*D
  const int d = (int)(idx & (DD - 1));
  const int l = (int)((idx >> 10) & (LL - 1));
  const float4 w = *(const float4*)(wc + d * 4);
  const ushort_t* xp = xin + idx;
  float acc = w.w * bf2f(xp[0]);
  if (l >= 1) acc += w.z * bf2f(xp[-DD]);
  if (l >= 2) acc += w.y * bf2f(xp[-2*DD]);
  if (l >= 3) acc += w.x * bf2f(xp[-3*DD]);
  acc = acc * sigm(acc);
  const int b = (int)(idx >> 22);
  const int h = d >> 8, dk = d & 255;
  outp[(((size_t)(b*HH + h))*LL + l)*DKk + dk] = f2bf(acc);
}

// ---- beta / g_s / g_l: 12 length-1024 dots per (b,l), x fp32 ---------------
__global__ __launch_bounds__(256) void small_proj_kernel(const float* __restrict__ x,
   const float* __restrict__ Wb, const float* __restrict__ Wds, const float* __restrict__ bds,
   const float* __restrict__ Wdl, const float* __restrict__ bdl,
   float* __restrict__ beta, float* __restrict__ gs, float* __restrict__ gl)
{
  const int bl = blockIdx.x;
  const int t = threadIdx.x, wave = t >> 6, lane = t & 63;
  __shared__ float res[12];
  const float* xr = x + (size_t)bl * DD + lane * 16;
  const float4 x0 = *(const float4*)(xr);
  const float4 x1 = *(const float4*)(xr + 4);
  const float4 x2 = *(const float4*)(xr + 8);
  const float4 x3 = *(const float4*)(xr + 12);
  for (int rr = 0; rr < 3; ++rr) {
    const int r = wave * 3 + rr;
    const int mat = r >> 2, h = r & 3;
    const float* Wr = (mat == 0 ? Wb : (mat == 1 ? Wds : Wdl)) + (size_t)h * DD + lane * 16;
    const float4 w0 = *(const float4*)(Wr);
    const float4 w1 = *(const float4*)(Wr + 4);
    const float4 w2 = *(const float4*)(Wr + 8);
    const float4 w3 = *(const float4*)(Wr + 12);
    float p = x0.x*w0.x + x0.y*w0.y + x0.z*w0.z + x0.w*w0.w
            + x1.x*w1.x + x1.y*w1.y + x1.z*w1.z + x1.w*w1.w
            + x2.x*w2.x + x2.y*w2.y + x2.z*w2.z + x2.w*w2.w
            + x3.x*w3.x + x3.y*w3.y + x3.z*w3.z + x3.w*w3.w;
#pragma unroll
    for (int o = 1; o < 64; o <<= 1) p += __shfl_xor(p, o);
    if (lane == 0) res[r] = p;
  }
  __syncthreads();
  if (t < 12) {
    const int mat = t >> 2, h = t & 3;
    float v = res[t];
    if (mat == 1) v += bds[h];
    if (mat == 2) v += bdl[h];
    v = sigm(v);
    const int b = bl >> 12, l = bl & (LL - 1);
    const size_t o = ((size_t)(b*HH + h))*LL + l;
    (mat == 0 ? beta : (mat == 1 ? gs : gl))[o] = v;
  }
}

// ---- hierarchical gate: z bf16, 24 length-512 dots + 2-way softmaxes -------
__global__ __launch_bounds__(256) void gate_kernel(const ushort_t* __restrict__ z,
  const float* __restrict__ Wc, const float* __restrict__ bc,
  const float* __restrict__ Wl, const float* __restrict__ bl_,
  const float* __restrict__ Wg, const float* __restrict__ bg,
  const float* __restrict__ ltc, const float* __restrict__ ltf,
  float* __restrict__ wgt)
{
  const int bl = blockIdx.x;
  const int t = threadIdx.x, wave = t >> 6, lane = t & 63;
  __shared__ float res[24];
  const uint4 zv = *(const uint4*)(z + (size_t)bl * HIDD + lane * 8);
  float zf[8]; unpack8(zv, zf);
  for (int rr = 0; rr < 6; ++rr) {
    const int r = wave * 6 + rr;
    const int mat = r >> 3, qi = r & 7;
    const float* Wr = (mat == 0 ? Wc : (mat == 1 ? Wl : Wg)) + (size_t)qi * HIDD + lane * 8;
    const float4 w0 = *(const float4*)(Wr);
    const float4 w1 = *(const float4*)(Wr + 4);
    float p = zf[0]*w0.x + zf[1]*w0.y + zf[2]*w0.z + zf[3]*w0.w
            + zf[4]*w1.x + zf[5]*w1.y + zf[6]*w1.z + zf[7]*w1.w;
#pragma unroll
    for (int o = 1; o < 64; o <<= 1) p += __shfl_xor(p, o);
    if (lane == 0) {
      const float* br = (mat == 0 ? bc : (mat == 1 ? bl_ : bg));
      res[r] = p + br[qi];
    }
  }
  __syncthreads();
  if (t < 4) {
    const float tc = logf(1.f + __expf(ltc[t])) + 1e-4f;
    const float tf = logf(1.f + __expf(ltf[t])) + 1e-4f;
    const float pg0 = sigm((res[2*t]     - res[2*t+1])     / tc);
    const float q0  = sigm((res[8+2*t]   - res[8+2*t+1])   / tf);
    const float r0  = sigm((res[16+2*t]  - res[16+2*t+1])  / tf);
    float* o = wgt + ((size_t)bl * HH + t) * 4;
    o[0] = pg0 * q0;         o[1] = pg0 * (1.f - q0);
    o[2] = (1.f - pg0) * r0; o[3] = (1.f - pg0) * (1.f - r0);
  }
}

// ---- chunk-local prep (bf16 LDS, stride 264): l2norm, attn(hi/lo bf16),
//      triangular solves; emits kT (dk-major) and uT (dv-major) for MFMA scan.
#define QS 264
__global__ __launch_bounds__(256) void prep_kernel(ushort_t* __restrict__ q,
    ushort_t* __restrict__ k, const ushort_t* __restrict__ v,
    const float* __restrict__ beta,
    ushort_t* __restrict__ u, ushort_t* __restrict__ w,
    ushort_t* __restrict__ ah, ushort_t* __restrict__ al)
{
  __shared__ ushort_t qb[32*QS];
  __shared__ ushort_t kb[32*QS];
  __shared__ float Lm[32*32];
  __shared__ float betas[32];
  const int bid = blockIdx.x;
  const int ci = bid & (NC - 1);
  const int bh = bid >> 7;
  const int t = threadIdx.x;
  const size_t base = ((size_t)bh * LL + ci*32) * DKk;
  if (t < 32) betas[t] = beta[(size_t)bh * LL + ci*32 + t];
  for (int i4 = t; i4 < 1024; i4 += 256) {
    const int r = i4 >> 5, e = (i4 & 31) * 8;
    *(uint4*)&qb[r*QS + e] = *(const uint4*)(q + base + r*256 + e);
    *(uint4*)&kb[r*QS + e] = *(const uint4*)(k + base + r*256 + e);
  }
  __syncthreads();
  {
    const int r = t >> 3, g = t & 7;
    float sq = 0.f, sk = 0.f;
    for (int e = g*32; e < g*32 + 32; ++e) {
      const float a = bf2f(qb[r*QS + e]); sq = fmaf(a, a, sq);
      const float c = bf2f(kb[r*QS + e]); sk = fmaf(c, c, sk);
    }
#pragma unroll
    for (int o = 1; o < 8; o <<= 1) { sq += __shfl_xor(sq, o); sk += __shfl_xor(sk, o); }
    const float rq = rsqrtf(sq + 1e-6f), rk = rsqrtf(sk + 1e-6f);
    for (int e = g*32; e < g*32 + 32; ++e) {
      qb[r*QS + e] = f2bf(bf2f(qb[r*QS + e]) * rq);
      kb[r*QS + e] = f2bf(bf2f(kb[r*QS + e]) * rk);
    }
  }
  __syncthreads();
  // write back normalized q (row-major, used as MFMA A-frags in scan)
  for (int i4 = t; i4 < 1024; i4 += 256) {
    const int r = i4 >> 5, e = (i4 & 31) * 8;
    *(uint4*)(q + base + r*256 + e) = *(const uint4*)&qb[r*QS + e];
  }
  // write kT (dk-major: [dk][cr]) into the k slab; thread t = dk
  {
    unsigned int pk[16];
#pragma unroll
    for (int j = 0; j < 16; ++j)
      pk[j] = (unsigned int)kb[(2*j)*QS + t] | ((unsigned int)kb[(2*j+1)*QS + t] << 16);
    uint4* kd = (uint4*)(k + base + (size_t)t*32);
#pragma unroll
    for (int j = 0; j < 4; ++j) kd[j] = ((const uint4*)pk)[j];
  }
  {
    const int j = t & 31, i0 = (t >> 5) * 4;
#pragma unroll
    for (int ii = 0; ii < 4; ++ii) {
      const int i = i0 + ii;
      float dq = 0.f, dk2 = 0.f;
      for (int e = 0; e < 256; ++e) {
        const float kj = bf2f(kb[j*QS + e]);
        dq  = fmaf(bf2f(qb[i*QS + e]), kj, dq);
        dk2 = fmaf(bf2f(kb[i*QS + e]), kj, dk2);
      }
      const float av = (j <= i) ? dq : 0.f;
      const ushort_t hh = f2bf(av);
      const size_t aoff = ((size_t)bh*NC + ci)*1024 + (size_t)i*32 + j;
      ah[aoff] = hh;
      al[aoff] = f2bf(av - bf2f(hh));
      Lm[i*32 + j] = (j < i) ? betas[i] * dk2 : 0.f;
    }
  }
  __syncthreads();
  {
    float cu[32], cw[32];
#pragma unroll
    for (int r = 0; r < 32; ++r) {
      cu[r] = bf2f(v[base + r*256 + t]) * betas[r];
      cw[r] = bf2f(kb[r*QS + t]) * betas[r];
    }
#pragma unroll
    for (int i = 1; i < 32; ++i) {
      float au = cu[i], aw = cw[i];
#pragma unroll
      for (int j = 0; j < i; ++j) {
        const float lm = Lm[i*32 + j];
        au = fmaf(-lm, cu[j], au);
        aw = fmaf(-lm, cw[j], aw);
      }
      cu[i] = au; cw[i] = aw;
    }
    // uT (dv-major: [dv][cr]); thread t = dv -> 64B contiguous
    {
      unsigned int pu[16];
#pragma unroll
      for (int j = 0; j < 16; ++j) pu[j] = pack2(cu[2*j], cu[2*j+1]);
      uint4* ud = (uint4*)(u + base + (size_t)t*32);
#pragma unroll
      for (int j = 0; j < 4; ++j) ud[j] = ((const uint4*)pu)[j];
    }
#pragma unroll
    for (int r = 0; r < 32; ++r) w[base + r*256 + t] = f2bf(cw[r]);
  }
}

// ---- MFMA sequential chunk scan --------------------------------------------
// 128 blocks = 16 bh x 8 dv-slices of 32. 4 waves/block.
// S (256dk x 32dv slice) lives in MFMA f32 accumulators (8 tiles/wave),
// mirrored each chunk into LDS as bf16 hi+lo (S = S_hi + S_lo, ~f32 precision).
// Per chunk: {uhat = u - w@S, o = q@S} fused (one pass over S frags),
// then attn@uhat + o write, then S += kT@(uhat_hi+uhat_lo). 2 barriers/chunk.
// sT rows are 512B -> XOR-swizzle (dv&7)<<4 to kill the 16-way bank conflict.
#define SIDX(ldv,kk) (((ldv)<<8) + ((kk) ^ (((ldv)&7)<<3)))
#define UIDX(ldv,cr) (((ldv)<<5) + ((cr) ^ (((ldv)&3)<<3)))

struct FragsD { short8 w[8]; uint2 ut; };

__global__ __launch_bounds__(256) void scan_kernel(
    const ushort_t* __restrict__ qn, const ushort_t* __restrict__ kt,
    const ushort_t* __restrict__ ut, const ushort_t* __restrict__ w,
    const ushort_t* __restrict__ ah, const ushort_t* __restrict__ al,
    float* __restrict__ dout)
{
  __shared__ ushort_t sT[2][32*256];   // [hi/lo][dv][dk], swizzled
  __shared__ ushort_t uhT[2][32*32];   // [hi/lo][dv][cr], swizzled
  const int bid = blockIdx.x;
  const int bh = bid & 15, vs = bid >> 4;  // same bh -> same XCD (bid%8 const)
  const int b = bh >> 2, h = bh & 3;
  const int t = threadIdx.x, lane = t & 63, wave = t >> 6;
  const int fr = lane & 15, fq = lane >> 4;
  const int mtA = wave >> 1, ntA = wave & 1;
  const int ldvA = ntA * 16 + fr;

  for (int i = t; i < 2048; i += 256) ((uint4*)sT)[i] = (uint4){0u,0u,0u,0u};

  const size_t bhL = (size_t)bh * LL;
  const ushort_t* wB  = w  + bhL * DKk;
  const ushort_t* qB  = qn + bhL * DKk;
  const ushort_t* kB  = kt + bhL * DKk;
  const ushort_t* uB  = ut + bhL * DVv;
  const ushort_t* ahB = ah + (size_t)bh * NC * 1024;
  const ushort_t* alB = al + (size_t)bh * NC * 1024;
  float* oB = dout + (size_t)b * LL * DD + h * DVv + vs * 32;

  floatx4 Sacc[8];
#pragma unroll
  for (int i = 0; i < 8; ++i) Sacc[i] = (floatx4){0.f,0.f,0.f,0.f};

  auto loadD = [&](int ci, FragsD& f) {
    const ushort_t* wp = wB + ((size_t)(ci*32 + mtA*16 + fr)) * DKk + fq*8;
#pragma unroll
    for (int ks = 0; ks < 8; ++ks) f.w[ks] = *(const short8*)(wp + ks*32);
    // u rows for this wave's output tile: cr = mtA*16 + fq*4 + reg
    f.ut = *(const uint2*)(uB + (size_t)ci*8192 + (size_t)(vs*32 + ldvA)*32 + mtA*16 + fq*4);
  };

  FragsD f0, f1;
  loadD(0, f0);
  __syncthreads();   // sT zero-init visible

  auto body = [&](int ci, FragsD& cur, FragsD& nxt) {
    if (ci + 1 < NC) loadD(ci + 1, nxt);               // prefetch next chunk
    short8 qf[8], kf[4], afh, afl;
    {
      const ushort_t* qp = qB + ((size_t)(ci*32 + mtA*16 + fr)) * DKk + fq*8;
#pragma unroll
      for (int ks = 0; ks < 8; ++ks) qf[ks] = *(const short8*)(qp + ks*32);
      const ushort_t* kp = kB + (size_t)ci*8192 + fq*8;
#pragma unroll
      for (int m = 0; m < 4; ++m)
        kf[m] = *(const short8*)(kp + (size_t)((wave*4+m)*16 + fr)*32);
      afh = *(const short8*)(ahB + (size_t)ci*1024 + (mtA*16+fr)*32 + fq*8);
      afl = *(const short8*)(alB + (size_t)ci*1024 + (mtA*16+fr)*32 + fq*8);
    }
    // fused: accA = -u + w@S (-> -uhat), accB = q@S
    floatx4 accA, accB = (floatx4){0.f,0.f,0.f,0.f};
    { float u0,u1,u2,u3; unpack2(cur.ut.x,u0,u1); unpack2(cur.ut.y,u2,u3);
      accA = (floatx4){-u0,-u1,-u2,-u3}; }
#pragma unroll
    for (int ks = 0; ks < 8; ++ks) {
      const short8 sh = *(const short8*)&sT[0][SIDX(ldvA, ks*32 + fq*8)];
      const short8 sl = *(const short8*)&sT[1][SIDX(ldvA, ks*32 + fq*8)];
      accA = __builtin_amdgcn_mfma_f32_16x16x32_bf16(cur.w[ks], sh, accA, 0,0,0);
      accA = __builtin_amdgcn_mfma_f32_16x16x32_bf16(cur.w[ks], sl, accA, 0,0,0);
      accB = __builtin_amdgcn_mfma_f32_16x16x32_bf16(qf[ks],    sh, accB, 0,0,0);
      accB = __builtin_amdgcn_mfma_f32_16x16x32_bf16(qf[ks],    sl, accB, 0,0,0);
    }
    // uhat = -accA; split hi/lo -> LDS
    {
      const float v0 = -accA[0], v1 = -accA[1], v2 = -accA[2], v3 = -accA[3];
      const ushort_t h0 = f2bf(v0), h1 = f2bf(v1), h2 = f2bf(v2), h3 = f2bf(v3);
      uint2 ph, pl;
      ph.x = (unsigned int)h0 | ((unsigned int)h1 << 16);
      ph.y = (unsigned int)h2 | ((unsigned int)h3 << 16);
      pl.x = pack2(v0 - bf2f(h0), v1 - bf2f(h1));
      pl.y = pack2(v2 - bf2f(h2), v3 - bf2f(h3));
      const int cr0 = mtA*16 + fq*4;
      *(uint2*)&uhT[0][UIDX(ldvA, cr0)] = ph;
      *(uint2*)&uhT[1][UIDX(ldvA, cr0)] = pl;
    }
    __syncthreads();   // BAR1: uhT ready; all sT reads of this chunk done
    // o = q@S + attn@uhat ; coalesced f32 write (16 consecutive dv per store)
    {
      const short8 uhh = *(const short8*)&uhT[0][UIDX(ldvA, fq*8)];
      const short8 uhl = *(const short8*)&uhT[1][UIDX(ldvA, fq*8)];
      accB = __builtin_amdgcn_mfma_f32_16x16x32_bf16(afh, uhh, accB, 0,0,0);
      accB = __builtin_amdgcn_mfma_f32_16x16x32_bf16(afh, uhl, accB, 0,0,0);
      accB = __builtin_amdgcn_mfma_f32_16x16x32_bf16(afl, uhh, accB, 0,0,0);
      float* op = oB + ((size_t)(ci*32 + mtA*16 + fq*4)) * DD + ntA*16 + fr;
#pragma unroll
      for (int r = 0; r < 4; ++r) op[(size_t)r * DD] = accB[r];
    }
    // S += kT @ (uhat_hi + uhat_lo)  (in-place f32 accumulators)
#pragma unroll
    for (int nt = 0; nt < 2; ++nt) {
      const int ldv = nt*16 + fr;
      const short8 bhf = *(const short8*)&uhT[0][UIDX(ldv, fq*8)];
      const short8 blf = *(const short8*)&uhT[1][UIDX(ldv, fq*8)];
#pragma unroll
      for (int m = 0; m < 4; ++m) {
        Sacc[m*2+nt] = __builtin_amdgcn_mfma_f32_16x16x32_bf16(kf[m], bhf, Sacc[m*2+nt], 0,0,0);
        Sacc[m*2+nt] = __builtin_amdgcn_mfma_f32_16x16x32_bf16(kf[m], blf, Sacc[m*2+nt], 0,0,0);
      }
    }
    // mirror S to LDS hi/lo for next chunk (sT readers finished before BAR1)
#pragma unroll
    for (int m = 0; m < 4; ++m)
#pragma unroll
      for (int nt = 0; nt < 2; ++nt) {
        const int ldv = nt*16 + fr;
        const int dk0 = (wave*4+m)*16 + fq*4;
        const floatx4 s = Sacc[m*2+nt];
        const ushort_t h0 = f2bf(s[0]), h1 = f2bf(s[1]), h2 = f2bf(s[2]), h3 = f2bf(s[3]);
        uint2 ph, pl;
        ph.x = (unsigned int)h0 | ((unsigned int)h1 << 16);
        ph.y = (unsigned int)h2 | ((unsigned int)h3 << 16);
        pl.x = pack2(s[0] - bf2f(h0), s[1] - bf2f(h1));
        pl.y = pack2(s[2] - bf2f(h2), s[3] - bf2f(h3));
        *(uint2*)&sT[0][SIDX(ldv, dk0)] = ph;
        *(uint2*)&sT[1][SIDX(ldv, dk0)] = pl;
      }
    __syncthreads();   // BAR2: sT ready; uhT readers done
  };

  for (int c2 = 0; c2 < NC; c2 += 2) { body(c2, f0, f1); body(c2+1, f1, f0); }
}

// ---- dual EMA scan (bf16 v in, bf16 es/el out) -----------------------------
__global__ __launch_bounds__(64) void ema_kernel(const ushort_t* __restrict__ v,
  const float* __restrict__ gs, const float* __restrict__ gl,
  ushort_t* __restrict__ es, ushort_t* __restrict__ el)
{
  const int bid = blockIdx.x;
  const int vb = bid & 3, bh = bid >> 2;
  const int b = bh >> 2, h = bh & 3;
  const int dv = vb * 64 + threadIdx.x;
  const ushort_t* vp  = v + ((size_t)bh * LL) * DVv + dv;
  const float* gsp = gs + (size_t)bh * LL;
  const float* glp = gl + (size_t)bh * LL;
  ushort_t* esp = es + ((size_t)b * LL) * DD + h*DVv + dv;
  ushort_t* elp = el + ((size_t)b * LL) * DD + h*DVv + dv;
  float s1 = 0.f, s2 = 0.f;
  for (int l = 0; l < LL; ++l) {
    const float vv = bf2f(vp[(size_t)l * DVv]);
    const float a = gsp[l], g2 = glp[l];
    s1 = fmaf(a,  s1, (1.f - a)  * vv);
    s2 = fmaf(g2, s2, (1.f - g2) * vv);
    esp[(size_t)l * DD] = f2bf(s1);
    elp[(size_t)l * DD] = f2bf(s2);
  }
}

// ---- combine + per-head RMSNorm (delta_o fp32 from d_out, rest bf16) -------
__global__ __launch_bounds__(64) void combine_kernel(const ushort_t* __restrict__ v,
  const ushort_t* __restrict__ es, const ushort_t* __restrict__ el,
  const float* __restrict__ dov, const float* __restrict__ wgt,
  const float* __restrict__ onw, ushort_t* __restrict__ outp)
{
  const int bid = blockIdx.x;
  const int h = bid & 3;
  const size_t bl = (size_t)(bid >> 2);
  const int lane = threadIdx.x;
  const size_t b = bl >> 12;
  const size_t l = bl & (LL - 1);
  const size_t vidx = (((b*HH + h) * (size_t)LL) + l) * DVv + lane*4;
  const size_t didx = bl * DD + h*DVv + lane*4;
  const uint2 vu = *(const uint2*)(v + vidx);
  const uint2 eu = *(const uint2*)(es + didx);
  const uint2 gu = *(const uint2*)(el + didx);
  const float4 d4 = *(const float4*)(dov + didx);
  float vf[4], ef[4], gf[4];
  unpack2(vu.x, vf[0], vf[1]); unpack2(vu.y, vf[2], vf[3]);
  unpack2(eu.x, ef[0], ef[1]); unpack2(eu.y, ef[2], ef[3]);
  unpack2(gu.x, gf[0], gf[1]); unpack2(gu.y, gf[2], gf[3]);
  const float* wp = wgt + (size_t)bid * 4;
  const float w0 = wp[0], w1 = wp[1], w2 = wp[2], w3 = wp[3];
  float o[4];
  const float df[4] = {d4.x, d4.y, d4.z, d4.w};
  float ss = 0.f;
#pragma unroll
  for (int i = 0; i < 4; ++i) {
    o[i] = w0*vf[i] + w1*ef[i] + w2*df[i] + w3*gf[i];
    ss = fmaf(o[i], o[i], ss);
  }
#pragma unroll
  for (int off = 1; off < 64; off <<= 1) ss += __shfl_xor(ss, off);
  const float sc = rsqrtf(ss * (1.f / DVv) + 1e-5f);
  const float4 nw = *(const float4*)(onw + lane*4);
  uint2 pk;
  pk.x = pack2(o[0]*sc*nw.x, o[1]*sc*nw.y);
  pk.y = pack2(o[2]*sc*nw.z, o[3]*sc*nw.w);
  *(uint2*)(outp + didx) = pk;
}

extern "C" void kernel_launch(void* const* d_in, const int* in_sizes, int n_in,
                              void* d_out, int out_size, void* d_ws, size_t ws_size,
                              hipStream_t stream)
{
  const float* x    = (const float*)d_in[0];
  const float* Wq   = (const float*)d_in[1];
  const float* Wk   = (const float*)d_in[2];
  const float* Wv   = (const float*)d_in[3];
  const float* cqw  = (const float*)d_in[4];
  const float* ckw  = (const float*)d_in[5];
  const float* cvw  = (const float*)d_in[6];
  const float* Wb   = (const float*)d_in[7];
  const float* Wds  = (const float*)d_in[8];
  const float* bds  = (const float*)d_in[9];
  const float* Wdl  = (const float*)d_in[10];
  const float* bdl  = (const float*)d_in[11];
  const float* Wtr  = (const float*)d_in[12];
  const float* btr  = (const float*)d_in[13];
  const float* Wc   = (const float*)d_in[14];
  const float* bc   = (const float*)d_in[15];
  const float* Wl   = (const float*)d_in[16];
  const float* blc  = (const float*)d_in[17];
  const float* Wg   = (const float*)d_in[18];
  const float* bg   = (const float*)d_in[19];
  const float* ltc  = (const float*)d_in[20];
  const float* ltf  = (const float*)d_in[21];
  const float* onw  = (const float*)d_in[22];
  const float* Wo   = (const float*)d_in[23];
  float* outp = (float*)d_out;

  const size_t BLD = (size_t)BB * LL * DD;
  unsigned char* w8 = (unsigned char*)d_ws;
  const size_t SL = BLD * 2;                        // 32 MB bf16 slab
  ushort_t* SA = (ushort_t*)(w8 + 0*SL);   // qraw -> kn -> kT -> opre
  ushort_t* SB = (ushort_t*)(w8 + 1*SL);   // kraw -> vv
  ushort_t* SC = (ushort_t*)(w8 + 2*SL);   // vraw -> uT
  ushort_t* SD = (ushort_t*)(w8 + 3*SL);   // qn -> el
  ushort_t* SE = (ushort_t*)(w8 + 4*SL);   // w  -> es
  ushort_t* zb   = (ushort_t*)(w8 + 5*SL);
  ushort_t* attn_hi = (ushort_t*)(w8 + 5*SL + BLD);
  ushort_t* attn_lo = attn_hi + (size_t)BB*HH*NC*1024;
  float*    beta = (float*)(attn_hi + 2*(size_t)BB*HH*NC*1024);
  float*    gs   = beta + (size_t)BB*HH*LL;
  float*    gl   = gs   + (size_t)BB*HH*LL;
  float*    wgt  = gl   + (size_t)BB*HH*LL;
  float*    dov  = outp;

  const int MBL = BB * LL;  // 16384
  dim3 blk256(256);

  gemm_mfma<0,1,0><<<dim3(DD/128, MBL/128), blk256, 0, stream>>>(x, Wq, nullptr, SA, MBL, DD, DD);
  gemm_mfma<0,1,0><<<dim3(DD/128, MBL/128), blk256, 0, stream>>>(x, Wk, nullptr, SB, MBL, DD, DD);
  gemm_mfma<0,1,0><<<dim3(DD/128, MBL/128), blk256, 0, stream>>>(x, Wv, nullptr, SC, MBL, DD, DD);
  gemm_mfma<1,1,0><<<dim3(HIDD/128, MBL/128), blk256, 0, stream>>>(x, Wtr, btr, zb, MBL, HIDD, DD);
  small_proj_kernel<<<dim3(MBL), blk256, 0, stream>>>(x, Wb, Wds, bds, Wdl, bdl, beta, gs, gl);
  gate_kernel<<<dim3(MBL), blk256, 0, stream>>>(zb, Wc, bc, Wl, blc, Wg, bg, ltc, ltf, wgt);
  conv_silu_kernel<<<dim3((unsigned)(BB*LL*DD/256)), blk256, 0, stream>>>(SA, cqw, SD);  // qn=SD
  conv_silu_kernel<<<dim3((unsigned)(BB*LL*DD/256)), blk256, 0, stream>>>(SB, ckw, SA);  // kn=SA
  conv_silu_kernel<<<dim3((unsigned)(BB*LL*DD/256)), blk256, 0, stream>>>(SC, cvw, SB);  // vv=SB
  prep_kernel<<<dim3(BB*HH*NC), blk256, 0, stream>>>(SD, SA, SB, beta, SC, SE, attn_hi, attn_lo); // uT=SC w=SE kT=SA
  scan_kernel<<<dim3(128), blk256, 0, stream>>>(SD, SA, SC, SE, attn_hi, attn_lo, dov);
  ema_kernel<<<dim3(BB*HH*4), dim3(64), 0, stream>>>(SB, gs, gl, SE, SD);                // es=SE el=SD
  combine_kernel<<<dim3(MBL*HH), dim3(64), 0, stream>>>(SB, SE, SD, dov, wgt, onw, SA);  // opre=SA
  gemm_mfma<0,0,1><<<dim3(DD/128, MBL/128), blk256, 0, stream>>>(SA, Wo, nullptr, outp, MBL, DD, DD);
}

// Round 3
// 1400.057 us; speedup vs baseline: 2.9223x; 1.3254x over previous
//
#include <hip/hip_runtime.h>
#include <math.h>

#define BB 4
#define LL 4096
#define DD 1024
#define HH 4
#define DKk 256
#define DVv 256
#define HIDD 512
#define NC 128   // number of 32-chunks in L
#define NSEG 64  // EMA segments
#define SEG 64   // EMA segment length

typedef unsigned short ushort_t;
typedef __attribute__((ext_vector_type(8))) short short8;
typedef __attribute__((ext_vector_type(4))) float floatx4;

__device__ __forceinline__ float sigm(float x) { return 1.f / (1.f + __expf(-x)); }

__device__ __forceinline__ float bf2f(ushort_t u) {
  union { unsigned int i; float f; } c; c.i = ((unsigned int)u) << 16; return c.f;
}
__device__ __forceinline__ ushort_t f2bf(float f) {
  union { float f; unsigned int i; } c; c.f = f;
  unsigned int lsb = (c.i >> 16) & 1u;
  return (ushort_t)((c.i + 0x7fffu + lsb) >> 16);
}
__device__ __forceinline__ void unpack2(unsigned int u, float& a, float& b) {
  union { unsigned int i; float f; } c0, c1;
  c0.i = u << 16; c1.i = u & 0xffff0000u; a = c0.f; b = c1.f;
}
__device__ __forceinline__ unsigned int pack2(float a, float b) {
  return (unsigned int)f2bf(a) | ((unsigned int)f2bf(b) << 16);
}
__device__ __forceinline__ void unpack8(const uint4 v, float* o) {
  unpack2(v.x, o[0], o[1]); unpack2(v.y, o[2], o[3]);
  unpack2(v.z, o[4], o[5]); unpack2(v.w, o[6], o[7]);
}

// ---- MFMA GEMM: C(M,N)=A(M,K)@W(N,K)^T. W fp32; A fp32 or bf16 (ABF16). ----
// BF16OUT: C stored bf16 else fp32.  ACT==1: +bias then SiLU.
template<int ACT, int BF16OUT, int ABF16>
__global__ __launch_bounds__(256) void gemm_mfma(const void* __restrict__ Av,
    const float* __restrict__ W, const float* __restrict__ bias,
    void* __restrict__ Cv, int M, int N, int K)
{
  __shared__ ushort_t As[128*32];
  __shared__ ushort_t Ws[128*32];
  const int tid = threadIdx.x;
  const int bm = blockIdx.y * 128, bn = blockIdx.x * 128;
  const int lane = tid & 63, wave = tid >> 6;
  const int wm = (wave >> 1) * 64, wn = (wave & 1) * 64;
  const int fr = lane & 15, fq = lane >> 4;     // frag row / k-quad
  const int sr = tid >> 1, kh = (tid & 1) * 16; // staging: row, k-half
  floatx4 acc[4][4];
#pragma unroll
  for (int i = 0; i < 4; ++i)
#pragma unroll
    for (int j = 0; j < 4; ++j) acc[i][j] = (floatx4){0.f, 0.f, 0.f, 0.f};

  for (int k0 = 0; k0 < K; k0 += 32) {
    uint4 pa0, pa1, pw0, pw1;
    if (ABF16) {
      const ushort_t* Ap = (const ushort_t*)Av + (size_t)(bm + sr) * K + k0 + kh;
      pa0 = *(const uint4*)(Ap);
      pa1 = *(const uint4*)(Ap + 8);
    } else {
      const float* Ap = (const float*)Av + (size_t)(bm + sr) * K + k0 + kh;
      const float4 a0 = *(const float4*)(Ap);     const float4 a1 = *(const float4*)(Ap + 4);
      const float4 a2 = *(const float4*)(Ap + 8); const float4 a3 = *(const float4*)(Ap + 12);
      pa0.x = pack2(a0.x, a0.y); pa0.y = pack2(a0.z, a0.w);
      pa0.z = pack2(a1.x, a1.y); pa0.w = pack2(a1.z, a1.w);
      pa1.x = pack2(a2.x, a2.y); pa1.y = pack2(a2.z, a2.w);
      pa1.z = pack2(a3.x, a3.y); pa1.w = pack2(a3.z, a3.w);
    }
    {
      const float* Wp = W + (size_t)(bn + sr) * K + k0 + kh;
      const float4 w0 = *(const float4*)(Wp);     const float4 w1 = *(const float4*)(Wp + 4);
      const float4 w2 = *(const float4*)(Wp + 8); const float4 w3 = *(const float4*)(Wp + 12);
      pw0.x = pack2(w0.x, w0.y); pw0.y = pack2(w0.z, w0.w);
      pw0.z = pack2(w1.x, w1.y); pw0.w = pack2(w1.z, w1.w);
      pw1.x = pack2(w2.x, w2.y); pw1.y = pack2(w2.z, w2.w);
      pw1.z = pack2(w3.x, w3.y); pw1.w = pack2(w3.z, w3.w);
    }
    __syncthreads();
    *(uint4*)&As[sr*32 + kh]     = pa0;
    *(uint4*)&As[sr*32 + kh + 8] = pa1;
    *(uint4*)&Ws[sr*32 + kh]     = pw0;
    *(uint4*)&Ws[sr*32 + kh + 8] = pw1;
    __syncthreads();
    short8 af[4], bf_[4];
#pragma unroll
    for (int mt = 0; mt < 4; ++mt)
      af[mt] = *(const short8*)&As[(wm + mt*16 + fr)*32 + fq*8];
#pragma unroll
    for (int nt = 0; nt < 4; ++nt)
      bf_[nt] = *(const short8*)&Ws[(wn + nt*16 + fr)*32 + fq*8];
#pragma unroll
    for (int mt = 0; mt < 4; ++mt)
#pragma unroll
      for (int nt = 0; nt < 4; ++nt)
        acc[mt][nt] = __builtin_amdgcn_mfma_f32_16x16x32_bf16(af[mt], bf_[nt], acc[mt][nt], 0, 0, 0);
  }
#pragma unroll
  for (int mt = 0; mt < 4; ++mt) {
#pragma unroll
    for (int reg = 0; reg < 4; ++reg) {
      const int row = bm + wm + mt*16 + fq*4 + reg;
#pragma unroll
      for (int nt = 0; nt < 4; ++nt) {
        const int col = bn + wn + nt*16 + fr;
        float v = acc[mt][nt][reg];
        if (ACT == 1) { v += bias[col]; v = v * sigm(v); }
        if (BF16OUT) ((ushort_t*)Cv)[(size_t)row * N + col] = f2bf(v);
        else         ((float*)Cv)[(size_t)row * N + col] = v;
      }
    }
  }
}

// ---- depthwise causal conv(k=4)+SiLU, bf16 in/out, relayout to (B,H,L,DK) --
__global__ __launch_bounds__(256) void conv_silu_kernel(const ushort_t* __restrict__ xin,
    const float* __restrict__ wc, ushort_t* __restrict__ outp)
{
  const size_t idx = (size_t)blockIdx.x * 256 + threadIdx.x;  // over B*L*D
  const int d = (int)(idx & (DD - 1));
  const int l = (int)((idx >> 10) & (LL - 1));
  const float4 w = *(const float4*)(wc + d * 4);
  const ushort_t* xp = xin + idx;
  float acc = w.w * bf2f(xp[0]);
  if (l >= 1) acc += w.z * bf2f(xp[-DD]);
  if (l >= 2) acc += w.y * bf2f(xp[-2*DD]);
  if (l >= 3) acc += w.x * bf2f(xp[-3*DD]);
  acc = acc * sigm(acc);
  const int b = (int)(idx >> 22);
  const int h = d >> 8, dk = d & 255;
  outp[(((size_t)(b*HH + h))*LL + l)*DKk + dk] = f2bf(acc);
}

// ---- beta / g_s / g_l: 12 length-1024 dots per (b,l), x fp32 ---------------
__global__ __launch_bounds__(256) void small_proj_kernel(const float* __restrict__ x,
   const float* __restrict__ Wb, const float* __restrict__ Wds, const float* __restrict__ bds,
   const float* __restrict__ Wdl, const float* __restrict__ bdl,
   float* __restrict__ beta, float* __restrict__ gs, float* __restrict__ gl)
{
  const int bl = blockIdx.x;
  const int t = threadIdx.x, wave = t >> 6, lane = t & 63;
  __shared__ float res[12];
  const float* xr = x + (size_t)bl * DD + lane * 16;
  const float4 x0 = *(const float4*)(xr);
  const float4 x1 = *(const float4*)(xr + 4);
  const float4 x2 = *(const float4*)(xr + 8);
  const float4 x3 = *(const float4*)(xr + 12);
  for (int rr = 0; rr < 3; ++rr) {
    const int r = wave * 3 + rr;
    const int mat = r >> 2, h = r & 3;
    const float* Wr = (mat == 0 ? Wb : (mat == 1 ? Wds : Wdl)) + (size_t)h * DD + lane * 16;
    const float4 w0 = *(const float4*)(Wr);
    const float4 w1 = *(const float4*)(Wr + 4);
    const float4 w2 = *(const float4*)(Wr + 8);
    const float4 w3 = *(const float4*)(Wr + 12);
    float p = x0.x*w0.x + x0.y*w0.y + x0.z*w0.z + x0.w*w0.w
            + x1.x*w1.x + x1.y*w1.y + x1.z*w1.z + x1.w*w1.w
            + x2.x*w2.x + x2.y*w2.y + x2.z*w2.z + x2.w*w2.w
            + x3.x*w3.x + x3.y*w3.y + x3.z*w3.z + x3.w*w3.w;
#pragma unroll
    for (int o = 1; o < 64; o <<= 1) p += __shfl_xor(p, o);
    if (lane == 0) res[r] = p;
  }
  __syncthreads();
  if (t < 12) {
    const int mat = t >> 2, h = t & 3;
    float v = res[t];
    if (mat == 1) v += bds[h];
    if (mat == 2) v += bdl[h];
    v = sigm(v);
    const int b = bl >> 12, l = bl & (LL - 1);
    const size_t o = ((size_t)(b*HH + h))*LL + l;
    (mat == 0 ? beta : (mat == 1 ? gs : gl))[o] = v;
  }
}

// ---- hierarchical gate: z bf16, 24 length-512 dots + 2-way softmaxes -------
__global__ __launch_bounds__(256) void gate_kernel(const ushort_t* __restrict__ z,
  const float* __restrict__ Wc, const float* __restrict__ bc,
  const float* __restrict__ Wl, const float* __restrict__ bl_,
  const float* __restrict__ Wg, const float* __restrict__ bg,
  const float* __restrict__ ltc, const float* __restrict__ ltf,
  float* __restrict__ wgt)
{
  const int bl = blockIdx.x;
  const int t = threadIdx.x, wave = t >> 6, lane = t & 63;
  __shared__ float res[24];
  const uint4 zv = *(const uint4*)(z + (size_t)bl * HIDD + lane * 8);
  float zf[8]; unpack8(zv, zf);
  for (int rr = 0; rr < 6; ++rr) {
    const int r = wave * 6 + rr;
    const int mat = r >> 3, qi = r & 7;
    const float* Wr = (mat == 0 ? Wc : (mat == 1 ? Wl : Wg)) + (size_t)qi * HIDD + lane * 8;
    const float4 w0 = *(const float4*)(Wr);
    const float4 w1 = *(const float4*)(Wr + 4);
    float p = zf[0]*w0.x + zf[1]*w0.y + zf[2]*w0.z + zf[3]*w0.w
            + zf[4]*w1.x + zf[5]*w1.y + zf[6]*w1.z + zf[7]*w1.w;
#pragma unroll
    for (int o = 1; o < 64; o <<= 1) p += __shfl_xor(p, o);
    if (lane == 0) {
      const float* br = (mat == 0 ? bc : (mat == 1 ? bl_ : bg));
      res[r] = p + br[qi];
    }
  }
  __syncthreads();
  if (t < 4) {
    const float tc = logf(1.f + __expf(ltc[t])) + 1e-4f;
    const float tf = logf(1.f + __expf(ltf[t])) + 1e-4f;
    const float pg0 = sigm((res[2*t]     - res[2*t+1])     / tc);
    const float q0  = sigm((res[8+2*t]   - res[8+2*t+1])   / tf);
    const float r0  = sigm((res[16+2*t]  - res[16+2*t+1])  / tf);
    float* o = wgt + ((size_t)bl * HH + t) * 4;
    o[0] = pg0 * q0;         o[1] = pg0 * (1.f - q0);
    o[2] = (1.f - pg0) * r0; o[3] = (1.f - pg0) * (1.f - r0);
  }
}

// ---- chunk-local prep (bf16 LDS, stride 264): l2norm, attn(hi/lo bf16),
//      triangular solves; emits kT (dk-major) and uT (dv-major) for MFMA scan.
#define QS 264
__global__ __launch_bounds__(256) void prep_kernel(ushort_t* __restrict__ q,
    ushort_t* __restrict__ k, const ushort_t* __restrict__ v,
    const float* __restrict__ beta,
    ushort_t* __restrict__ u, ushort_t* __restrict__ w,
    ushort_t* __restrict__ ah, ushort_t* __restrict__ al)
{
  __shared__ ushort_t qb[32*QS];
  __shared__ ushort_t kb[32*QS];
  __shared__ float Lm[32*32];
  __shared__ float betas[32];
  const int bid = blockIdx.x;
  const int ci = bid & (NC - 1);
  const int bh = bid >> 7;
  const int t = threadIdx.x;
  const size_t base = ((size_t)bh * LL + ci*32) * DKk;
  if (t < 32) betas[t] = beta[(size_t)bh * LL + ci*32 + t];
  for (int i4 = t; i4 < 1024; i4 += 256) {
    const int r = i4 >> 5, e = (i4 & 31) * 8;
    *(uint4*)&qb[r*QS + e] = *(const uint4*)(q + base + r*256 + e);
    *(uint4*)&kb[r*QS + e] = *(const uint4*)(k + base + r*256 + e);
  }
  __syncthreads();
  {
    const int r = t >> 3, g = t & 7;
    float sq = 0.f, sk = 0.f;
    for (int e = g*32; e < g*32 + 32; ++e) {
      const float a = bf2f(qb[r*QS + e]); sq = fmaf(a, a, sq);
      const float c = bf2f(kb[r*QS + e]); sk = fmaf(c, c, sk);
    }
#pragma unroll
    for (int o = 1; o < 8; o <<= 1) { sq += __shfl_xor(sq, o); sk += __shfl_xor(sk, o); }
    const float rq = rsqrtf(sq + 1e-6f), rk = rsqrtf(sk + 1e-6f);
    for (int e = g*32; e < g*32 + 32; ++e) {
      qb[r*QS + e] = f2bf(bf2f(qb[r*QS + e]) * rq);
      kb[r*QS + e] = f2bf(bf2f(kb[r*QS + e]) * rk);
    }
  }
  __syncthreads();
  // write back normalized q (row-major, used as MFMA A-frags in scan)
  for (int i4 = t; i4 < 1024; i4 += 256) {
    const int r = i4 >> 5, e = (i4 & 31) * 8;
    *(uint4*)(q + base + r*256 + e) = *(const uint4*)&qb[r*QS + e];
  }
  // write kT (dk-major: [dk][cr]) into the k slab; thread t = dk
  {
    unsigned int pk[16];
#pragma unroll
    for (int j = 0; j < 16; ++j)
      pk[j] = (unsigned int)kb[(2*j)*QS + t] | ((unsigned int)kb[(2*j+1)*QS + t] << 16);
    uint4* kd = (uint4*)(k + base + (size_t)t*32);
#pragma unroll
    for (int j = 0; j < 4; ++j) kd[j] = ((const uint4*)pk)[j];
  }
  {
    const int j = t & 31, i0 = (t >> 5) * 4;
#pragma unroll
    for (int ii = 0; ii < 4; ++ii) {
      const int i = i0 + ii;
      float dq = 0.f, dk2 = 0.f;
      for (int e = 0; e < 256; ++e) {
        const float kj = bf2f(kb[j*QS + e]);
        dq  = fmaf(bf2f(qb[i*QS + e]), kj, dq);
        dk2 = fmaf(bf2f(kb[i*QS + e]), kj, dk2);
      }
      const float av = (j <= i) ? dq : 0.f;
      const ushort_t hh = f2bf(av);
      const size_t aoff = ((size_t)bh*NC + ci)*1024 + (size_t)i*32 + j;
      ah[aoff] = hh;
      al[aoff] = f2bf(av - bf2f(hh));
      Lm[i*32 + j] = (j < i) ? betas[i] * dk2 : 0.f;
    }
  }
  __syncthreads();
  {
    float cu[32], cw[32];
#pragma unroll
    for (int r = 0; r < 32; ++r) {
      cu[r] = bf2f(v[base + r*256 + t]) * betas[r];
      cw[r] = bf2f(kb[r*QS + t]) * betas[r];
    }
#pragma unroll
    for (int i = 1; i < 32; ++i) {
      float au = cu[i], aw = cw[i];
#pragma unroll
      for (int j = 0; j < i; ++j) {
        const float lm = Lm[i*32 + j];
        au = fmaf(-lm, cu[j], au);
        aw = fmaf(-lm, cw[j], aw);
      }
      cu[i] = au; cw[i] = aw;
    }
    // uT (dv-major: [dv][cr]); thread t = dv -> 64B contiguous
    {
      unsigned int pu[16];
#pragma unroll
      for (int j = 0; j < 16; ++j) pu[j] = pack2(cu[2*j], cu[2*j+1]);
      uint4* ud = (uint4*)(u + base + (size_t)t*32);
#pragma unroll
      for (int j = 0; j < 4; ++j) ud[j] = ((const uint4*)pu)[j];
    }
#pragma unroll
    for (int r = 0; r < 32; ++r) w[base + r*256 + t] = f2bf(cw[r]);
  }
}

// ---- MFMA sequential chunk scan --------------------------------------------
#define SIDX(ldv,kk) (((ldv)<<8) + ((kk) ^ (((ldv)&7)<<3)))
#define UIDX(ldv,cr) (((ldv)<<5) + ((cr) ^ (((ldv)&3)<<3)))

struct FragsD { short8 w[8]; uint2 ut; };

__global__ __launch_bounds__(256) void scan_kernel(
    const ushort_t* __restrict__ qn, const ushort_t* __restrict__ kt,
    const ushort_t* __restrict__ ut, const ushort_t* __restrict__ w,
    const ushort_t* __restrict__ ah, const ushort_t* __restrict__ al,
    float* __restrict__ dout)
{
  __shared__ ushort_t sT[2][32*256];   // [hi/lo][dv][dk], swizzled
  __shared__ ushort_t uhT[2][32*32];   // [hi/lo][dv][cr], swizzled
  const int bid = blockIdx.x;
  const int bh = bid & 15, vs = bid >> 4;  // same bh -> same XCD (bid%8 const)
  const int b = bh >> 2, h = bh & 3;
  const int t = threadIdx.x, lane = t & 63, wave = t >> 6;
  const int fr = lane & 15, fq = lane >> 4;
  const int mtA = wave >> 1, ntA = wave & 1;
  const int ldvA = ntA * 16 + fr;

  for (int i = t; i < 2048; i += 256) ((uint4*)sT)[i] = (uint4){0u,0u,0u,0u};

  const size_t bhL = (size_t)bh * LL;
  const ushort_t* wB  = w  + bhL * DKk;
  const ushort_t* qB  = qn + bhL * DKk;
  const ushort_t* kB  = kt + bhL * DKk;
  const ushort_t* uB  = ut + bhL * DVv;
  const ushort_t* ahB = ah + (size_t)bh * NC * 1024;
  const ushort_t* alB = al + (size_t)bh * NC * 1024;
  float* oB = dout + (size_t)b * LL * DD + h * DVv + vs * 32;

  floatx4 Sacc[8];
#pragma unroll
  for (int i = 0; i < 8; ++i) Sacc[i] = (floatx4){0.f,0.f,0.f,0.f};

  auto loadD = [&](int ci, FragsD& f) {
    const ushort_t* wp = wB + ((size_t)(ci*32 + mtA*16 + fr)) * DKk + fq*8;
#pragma unroll
    for (int ks = 0; ks < 8; ++ks) f.w[ks] = *(const short8*)(wp + ks*32);
    // u rows for this wave's output tile: cr = mtA*16 + fq*4 + reg
    f.ut = *(const uint2*)(uB + (size_t)ci*8192 + (size_t)(vs*32 + ldvA)*32 + mtA*16 + fq*4);
  };

  FragsD f0, f1;
  loadD(0, f0);
  __syncthreads();   // sT zero-init visible

  auto body = [&](int ci, FragsD& cur, FragsD& nxt) {
    if (ci + 1 < NC) loadD(ci + 1, nxt);               // prefetch next chunk
    short8 qf[8], kf[4], afh, afl;
    {
      const ushort_t* qp = qB + ((size_t)(ci*32 + mtA*16 + fr)) * DKk + fq*8;
#pragma unroll
      for (int ks = 0; ks < 8; ++ks) qf[ks] = *(const short8*)(qp + ks*32);
      const ushort_t* kp = kB + (size_t)ci*8192 + fq*8;
#pragma unroll
      for (int m = 0; m < 4; ++m)
        kf[m] = *(const short8*)(kp + (size_t)((wave*4+m)*16 + fr)*32);
      afh = *(const short8*)(ahB + (size_t)ci*1024 + (mtA*16+fr)*32 + fq*8);
      afl = *(const short8*)(alB + (size_t)ci*1024 + (mtA*16+fr)*32 + fq*8);
    }
    // fused: accA = -u + w@S (-> -uhat), accB = q@S
    floatx4 accA, accB = (floatx4){0.f,0.f,0.f,0.f};
    { float u0,u1,u2,u3; unpack2(cur.ut.x,u0,u1); unpack2(cur.ut.y,u2,u3);
      accA = (floatx4){-u0,-u1,-u2,-u3}; }
#pragma unroll
    for (int ks = 0; ks < 8; ++ks) {
      const short8 sh = *(const short8*)&sT[0][SIDX(ldvA, ks*32 + fq*8)];
      const short8 sl = *(const short8*)&sT[1][SIDX(ldvA, ks*32 + fq*8)];
      accA = __builtin_amdgcn_mfma_f32_16x16x32_bf16(cur.w[ks], sh, accA, 0,0,0);
      accA = __builtin_amdgcn_mfma_f32_16x16x32_bf16(cur.w[ks], sl, accA, 0,0,0);
      accB = __builtin_amdgcn_mfma_f32_16x16x32_bf16(qf[ks],    sh, accB, 0,0,0);
      accB = __builtin_amdgcn_mfma_f32_16x16x32_bf16(qf[ks],    sl, accB, 0,0,0);
    }
    // uhat = -accA; split hi/lo -> LDS
    {
      const float v0 = -accA[0], v1 = -accA[1], v2 = -accA[2], v3 = -accA[3];
      const ushort_t h0 = f2bf(v0), h1 = f2bf(v1), h2 = f2bf(v2), h3 = f2bf(v3);
      uint2 ph, pl;
      ph.x = (unsigned int)h0 | ((unsigned int)h1 << 16);
      ph.y = (unsigned int)h2 | ((unsigned int)h3 << 16);
      pl.x = pack2(v0 - bf2f(h0), v1 - bf2f(h1));
      pl.y = pack2(v2 - bf2f(h2), v3 - bf2f(h3));
      const int cr0 = mtA*16 + fq*4;
      *(uint2*)&uhT[0][UIDX(ldvA, cr0)] = ph;
      *(uint2*)&uhT[1][UIDX(ldvA, cr0)] = pl;
    }
    __syncthreads();   // BAR1: uhT ready; all sT reads of this chunk done
    // o = q@S + attn@uhat ; coalesced f32 write (16 consecutive dv per store)
    {
      const short8 uhh = *(const short8*)&uhT[0][UIDX(ldvA, fq*8)];
      const short8 uhl = *(const short8*)&uhT[1][UIDX(ldvA, fq*8)];
      accB = __builtin_amdgcn_mfma_f32_16x16x32_bf16(afh, uhh, accB, 0,0,0);
      accB = __builtin_amdgcn_mfma_f32_16x16x32_bf16(afh, uhl, accB, 0,0,0);
      accB = __builtin_amdgcn_mfma_f32_16x16x32_bf16(afl, uhh, accB, 0,0,0);
      float* op = oB + ((size_t)(ci*32 + mtA*16 + fq*4)) * DD + ntA*16 + fr;
#pragma unroll
      for (int r = 0; r < 4; ++r) op[(size_t)r * DD] = accB[r];
    }
    // S += kT @ (uhat_hi + uhat_lo)  (in-place f32 accumulators)
#pragma unroll
    for (int nt = 0; nt < 2; ++nt) {
      const int ldv = nt*16 + fr;
      const short8 bhf = *(const short8*)&uhT[0][UIDX(ldv, fq*8)];
      const short8 blf = *(const short8*)&uhT[1][UIDX(ldv, fq*8)];
#pragma unroll
      for (int m = 0; m < 4; ++m) {
        Sacc[m*2+nt] = __builtin_amdgcn_mfma_f32_16x16x32_bf16(kf[m], bhf, Sacc[m*2+nt], 0,0,0);
        Sacc[m*2+nt] = __builtin_amdgcn_mfma_f32_16x16x32_bf16(kf[m], blf, Sacc[m*2+nt], 0,0,0);
      }
    }
    // mirror S to LDS hi/lo for next chunk (sT readers finished before BAR1)
#pragma unroll
    for (int m = 0; m < 4; ++m)
#pragma unroll
      for (int nt = 0; nt < 2; ++nt) {
        const int ldv = nt*16 + fr;
        const int dk0 = (wave*4+m)*16 + fq*4;
        const floatx4 s = Sacc[m*2+nt];
        const ushort_t h0 = f2bf(s[0]), h1 = f2bf(s[1]), h2 = f2bf(s[2]), h3 = f2bf(s[3]);
        uint2 ph, pl;
        ph.x = (unsigned int)h0 | ((unsigned int)h1 << 16);
        ph.y = (unsigned int)h2 | ((unsigned int)h3 << 16);
        pl.x = pack2(s[0] - bf2f(h0), s[1] - bf2f(h1));
        pl.y = pack2(s[2] - bf2f(h2), s[3] - bf2f(h3));
        *(uint2*)&sT[0][SIDX(ldv, dk0)] = ph;
        *(uint2*)&sT[1][SIDX(ldv, dk0)] = pl;
      }
    __syncthreads();   // BAR2: sT ready; uhT readers done
  };

  for (int c2 = 0; c2 < NC; c2 += 2) { body(c2, f0, f1); body(c2+1, f1, f0); }
}

// ---- EMA pass 1: per-segment local scan ------------------------------------
// grid: bh(16) x NSEG(64); 256 threads = one dv each. Writes bf16 local
// values into es/el slabs, segment-end B vectors, segment-product A scalars,
// and within-segment prefix products Pref (scalar per (bh,l)).
__global__ __launch_bounds__(256) void ema_local_kernel(const ushort_t* __restrict__ v,
  const float* __restrict__ gs, const float* __restrict__ gl,
  ushort_t* __restrict__ es, ushort_t* __restrict__ el,
  float* __restrict__ Bs, float* __restrict__ Bl,
  float* __restrict__ As, float* __restrict__ Al,
  float* __restrict__ PfS, float* __restrict__ PfL)
{
  const int bid = blockIdx.x;
  const int seg = bid & (NSEG - 1), bh = bid >> 6;
  const int b = bh >> 2, h = bh & 3;
  const int dv = threadIdx.x;
  const int l0 = seg * SEG;
  const ushort_t* vp = v + ((size_t)bh*LL + l0) * DVv + dv;
  const float* gsp = gs + (size_t)bh*LL + l0;
  const float* glp = gl + (size_t)bh*LL + l0;
  ushort_t* esp = es + ((size_t)b*LL + l0)*DD + h*DVv + dv;
  ushort_t* elp = el + ((size_t)b*LL + l0)*DD + h*DVv + dv;
  float* pfs = PfS + (size_t)bh*LL + l0;
  float* pfl = PfL + (size_t)bh*LL + l0;
  float s1 = 0.f, s2 = 0.f, p1 = 1.f, p2 = 1.f;
  for (int j = 0; j < SEG; ++j) {
    const float vv = bf2f(vp[(size_t)j * DVv]);
    const float a = gsp[j], g2 = glp[j];
    s1 = fmaf(a,  s1, (1.f - a)  * vv);
    s2 = fmaf(g2, s2, (1.f - g2) * vv);
    p1 *= a; p2 *= g2;
    esp[(size_t)j * DD] = f2bf(s1);
    elp[(size_t)j * DD] = f2bf(s2);
    if (dv == 0) { pfs[j] = p1; pfl[j] = p2; }
  }
  const size_t o = (((size_t)bh*NSEG + seg) << 8) + dv;
  Bs[o] = s1; Bl[o] = s2;
  if (dv == 0) { As[bh*NSEG + seg] = p1; Al[bh*NSEG + seg] = p2; }
}

// ---- EMA pass 2: cross-segment carry (carry INTO each segment) -------------
__global__ __launch_bounds__(256) void ema_carry_kernel(
  const float* __restrict__ Bs, const float* __restrict__ Bl,
  const float* __restrict__ As, const float* __restrict__ Al,
  float* __restrict__ Cs, float* __restrict__ Cl)
{
  const int bh = blockIdx.x;
  const int dv = threadIdx.x;
  __shared__ float Ash[NSEG], Alh[NSEG];
  if (dv < NSEG) { Ash[dv] = As[bh*NSEG + dv]; Alh[dv] = Al[bh*NSEG + dv]; }
  __syncthreads();
  float c1 = 0.f, c2 = 0.f;
  for (int s = 0; s < NSEG; ++s) {
    const size_t o = (((size_t)bh*NSEG + s) << 8) + dv;
    Cs[o] = c1; Cl[o] = c2;
    c1 = fmaf(Ash[s], c1, Bs[o]);
    c2 = fmaf(Alh[s], c2, Bl[o]);
  }
}

// ---- combine + per-head RMSNorm; fuses EMA segment-carry correction --------
__global__ __launch_bounds__(64) void combine_kernel(const ushort_t* __restrict__ v,
  const ushort_t* __restrict__ es, const ushort_t* __restrict__ el,
  const float* __restrict__ dov, const float* __restrict__ wgt,
  const float* __restrict__ onw,
  const float* __restrict__ Cs, const float* __restrict__ Cl,
  const float* __restrict__ PfS, const float* __restrict__ PfL,
  ushort_t* __restrict__ outp)
{
  const int bid = blockIdx.x;
  const int h = bid & 3;
  const size_t bl = (size_t)(bid >> 2);
  const int lane = threadIdx.x;
  const size_t b = bl >> 12;
  const size_t l = bl & (LL - 1);
  const int bh = (int)(b * HH) + h;
  const int seg = (int)(l >> 6);
  const size_t vidx = (((b*HH + h) * (size_t)LL) + l) * DVv + lane*4;
  const size_t didx = bl * DD + h*DVv + lane*4;
  const uint2 vu = *(const uint2*)(v + vidx);
  const uint2 eu = *(const uint2*)(es + didx);
  const uint2 gu = *(const uint2*)(el + didx);
  const float4 d4 = *(const float4*)(dov + didx);
  const float pS = PfS[(size_t)bh*LL + l];
  const float pL = PfL[(size_t)bh*LL + l];
  const float4 cs4 = *(const float4*)(Cs + (((size_t)bh*NSEG + seg) << 8) + lane*4);
  const float4 cl4 = *(const float4*)(Cl + (((size_t)bh*NSEG + seg) << 8) + lane*4);
  float vf[4], ef[4], gf[4];
  unpack2(vu.x, vf[0], vf[1]); unpack2(vu.y, vf[2], vf[3]);
  unpack2(eu.x, ef[0], ef[1]); unpack2(eu.y, ef[2], ef[3]);
  unpack2(gu.x, gf[0], gf[1]); unpack2(gu.y, gf[2], gf[3]);
  ef[0] = fmaf(pS, cs4.x, ef[0]); ef[1] = fmaf(pS, cs4.y, ef[1]);
  ef[2] = fmaf(pS, cs4.z, ef[2]); ef[3] = fmaf(pS, cs4.w, ef[3]);
  gf[0] = fmaf(pL, cl4.x, gf[0]); gf[1] = fmaf(pL, cl4.y, gf[1]);
  gf[2] = fmaf(pL, cl4.z, gf[2]); gf[3] = fmaf(pL, cl4.w, gf[3]);
  const float* wp = wgt + (size_t)bid * 4;
  const float w0 = wp[0], w1 = wp[1], w2 = wp[2], w3 = wp[3];
  float o[4];
  const float df[4] = {d4.x, d4.y, d4.z, d4.w};
  float ss = 0.f;
#pragma unroll
  for (int i = 0; i < 4; ++i) {
    o[i] = w0*vf[i] + w1*ef[i] + w2*df[i] + w3*gf[i];
    ss = fmaf(o[i], o[i], ss);
  }
#pragma unroll
  for (int off = 1; off < 64; off <<= 1) ss += __shfl_xor(ss, off);
  const float sc = rsqrtf(ss * (1.f / DVv) + 1e-5f);
  const float4 nw = *(const float4*)(onw + lane*4);
  uint2 pk;
  pk.x = pack2(o[0]*sc*nw.x, o[1]*sc*nw.y);
  pk.y = pack2(o[2]*sc*nw.z, o[3]*sc*nw.w);
  *(uint2*)(outp + didx) = pk;
}

extern "C" void kernel_launch(void* const* d_in, const int* in_sizes, int n_in,
                              void* d_out, int out_size, void* d_ws, size_t ws_size,
                              hipStream_t stream)
{
  const float* x    = (const float*)d_in[0];
  const float* Wq   = (const float*)d_in[1];
  const float* Wk   = (const float*)d_in[2];
  const float* Wv   = (const float*)d_in[3];
  const float* cqw  = (const float*)d_in[4];
  const float* ckw  = (const float*)d_in[5];
  const float* cvw  = (const float*)d_in[6];
  const float* Wb   = (const float*)d_in[7];
  const float* Wds  = (const float*)d_in[8];
  const float* bds  = (const float*)d_in[9];
  const float* Wdl  = (const float*)d_in[10];
  const float* bdl  = (const float*)d_in[11];
  const float* Wtr  = (const float*)d_in[12];
  const float* btr  = (const float*)d_in[13];
  const float* Wc   = (const float*)d_in[14];
  const float* bc   = (const float*)d_in[15];
  const float* Wl   = (const float*)d_in[16];
  const float* blc  = (const float*)d_in[17];
  const float* Wg   = (const float*)d_in[18];
  const float* bg   = (const float*)d_in[19];
  const float* ltc  = (const float*)d_in[20];
  const float* ltf  = (const float*)d_in[21];
  const float* onw  = (const float*)d_in[22];
  const float* Wo   = (const float*)d_in[23];
  float* outp = (float*)d_out;

  const size_t BLD = (size_t)BB * LL * DD;
  unsigned char* w8 = (unsigned char*)d_ws;
  const size_t SL = BLD * 2;                        // 32 MB bf16 slab
  ushort_t* SA = (ushort_t*)(w8 + 0*SL);   // qraw -> kn -> kT -> opre
  ushort_t* SB = (ushort_t*)(w8 + 1*SL);   // kraw -> vv
  ushort_t* SC = (ushort_t*)(w8 + 2*SL);   // vraw -> uT
  ushort_t* SD = (ushort_t*)(w8 + 3*SL);   // qn -> el(local)
  ushort_t* SE = (ushort_t*)(w8 + 4*SL);   // w  -> es(local)
  ushort_t* zb   = (ushort_t*)(w8 + 5*SL);
  ushort_t* attn_hi = (ushort_t*)(w8 + 5*SL + BLD);
  ushort_t* attn_lo = attn_hi + (size_t)BB*HH*NC*1024;
  float*    beta = (float*)(attn_hi + 2*(size_t)BB*HH*NC*1024);
  float*    gs   = beta + (size_t)BB*HH*LL;
  float*    gl   = gs   + (size_t)BB*HH*LL;
  float*    wgt  = gl   + (size_t)BB*HH*LL;
  float*    Bs   = wgt  + (size_t)BB*LL*HH*4;
  float*    Bl   = Bs   + (size_t)BB*HH*NSEG*256;
  float*    Cs   = Bl   + (size_t)BB*HH*NSEG*256;
  float*    Cl   = Cs   + (size_t)BB*HH*NSEG*256;
  float*    As   = Cl   + (size_t)BB*HH*NSEG*256;
  float*    Al   = As   + (size_t)BB*HH*NSEG;
  float*    PfS  = Al   + (size_t)BB*HH*NSEG;
  float*    PfL  = PfS  + (size_t)BB*HH*LL;
  float*    dov  = outp;

  const int MBL = BB * LL;  // 16384
  dim3 blk256(256);

  gemm_mfma<0,1,0><<<dim3(DD/128, MBL/128), blk256, 0, stream>>>(x, Wq, nullptr, SA, MBL, DD, DD);
  gemm_mfma<0,1,0><<<dim3(DD/128, MBL/128), blk256, 0, stream>>>(x, Wk, nullptr, SB, MBL, DD, DD);
  gemm_mfma<0,1,0><<<dim3(DD/128, MBL/128), blk256, 0, stream>>>(x, Wv, nullptr, SC, MBL, DD, DD);
  gemm_mfma<1,1,0><<<dim3(HIDD/128, MBL/128), blk256, 0, stream>>>(x, Wtr, btr, zb, MBL, HIDD, DD);
  small_proj_kernel<<<dim3(MBL), blk256, 0, stream>>>(x, Wb, Wds, bds, Wdl, bdl, beta, gs, gl);
  gate_kernel<<<dim3(MBL), blk256, 0, stream>>>(zb, Wc, bc, Wl, blc, Wg, bg, ltc, ltf, wgt);
  conv_silu_kernel<<<dim3((unsigned)(BB*LL*DD/256)), blk256, 0, stream>>>(SA, cqw, SD);  // qn=SD
  conv_silu_kernel<<<dim3((unsigned)(BB*LL*DD/256)), blk256, 0, stream>>>(SB, ckw, SA);  // kn=SA
  conv_silu_kernel<<<dim3((unsigned)(BB*LL*DD/256)), blk256, 0, stream>>>(SC, cvw, SB);  // vv=SB
  prep_kernel<<<dim3(BB*HH*NC), blk256, 0, stream>>>(SD, SA, SB, beta, SC, SE, attn_hi, attn_lo); // uT=SC w=SE kT=SA
  scan_kernel<<<dim3(128), blk256, 0, stream>>>(SD, SA, SC, SE, attn_hi, attn_lo, dov);
  ema_local_kernel<<<dim3(BB*HH*NSEG), blk256, 0, stream>>>(SB, gs, gl, SE, SD, Bs, Bl, As, Al, PfS, PfL); // es=SE el=SD
  ema_carry_kernel<<<dim3(BB*HH), blk256, 0, stream>>>(Bs, Bl, As, Al, Cs, Cl);
  combine_kernel<<<dim3(MBL*HH), dim3(64), 0, stream>>>(SB, SE, SD, dov, wgt, onw, Cs, Cl, PfS, PfL, SA); // opre=SA
  gemm_mfma<0,0,1><<<dim3(DD/128, MBL/128), blk256, 0, stream>>>(SA, Wo, nullptr, outp, MBL, DD, DD);
}

// Round 4
// 1291.209 us; speedup vs baseline: 3.1686x; 1.0843x over previous
//
#include <hip/hip_runtime.h>
#include <math.h>

#define BB 4
#define LL 4096
#define DD 1024
#define HH 4
#define DKk 256
#define DVv 256
#define HIDD 512
#define NC 128   // number of 32-chunks in L
#define NSEG 64  // EMA segments
#define SEG 64   // EMA segment length

typedef unsigned short ushort_t;
typedef __attribute__((ext_vector_type(8))) short short8;
typedef __attribute__((ext_vector_type(4))) float floatx4;

__device__ __forceinline__ float sigm(float x) { return 1.f / (1.f + __expf(-x)); }

__device__ __forceinline__ float bf2f(ushort_t u) {
  union { unsigned int i; float f; } c; c.i = ((unsigned int)u) << 16; return c.f;
}
__device__ __forceinline__ ushort_t f2bf(float f) {
  union { float f; unsigned int i; } c; c.f = f;
  unsigned int lsb = (c.i >> 16) & 1u;
  return (ushort_t)((c.i + 0x7fffu + lsb) >> 16);
}
__device__ __forceinline__ void unpack2(unsigned int u, float& a, float& b) {
  union { unsigned int i; float f; } c0, c1;
  c0.i = u << 16; c1.i = u & 0xffff0000u; a = c0.f; b = c1.f;
}
__device__ __forceinline__ unsigned int pack2(float a, float b) {
  return (unsigned int)f2bf(a) | ((unsigned int)f2bf(b) << 16);
}
__device__ __forceinline__ void unpack8(const uint4 v, float* o) {
  unpack2(v.x, o[0], o[1]); unpack2(v.y, o[2], o[3]);
  unpack2(v.z, o[4], o[5]); unpack2(v.w, o[6], o[7]);
}
__device__ __forceinline__ float ubits(unsigned u) {
  union { unsigned i; float f; } c; c.i = u; return c.f;
}
// exact truncate-split of two floats into packed bf16 hi and bf16 lo words
__device__ __forceinline__ void split2t(float a, float b, unsigned& hi, unsigned& lo) {
  union { float f; unsigned u; } ca, cb; ca.f = a; cb.f = b;
  const unsigned ha = ca.u & 0xffff0000u, hb = cb.u & 0xffff0000u;
  hi = (ha >> 16) | hb;
  union { float f; unsigned u; } la, lb;
  la.f = a - ubits(ha); lb.f = b - ubits(hb);
  lo = (la.u >> 16) | (lb.u & 0xffff0000u);
}
__device__ __forceinline__ void gload16(const ushort_t* g, ushort_t* l) {
  __builtin_amdgcn_global_load_lds(
      (const __attribute__((address_space(1))) void*)g,
      (__attribute__((address_space(3))) void*)l, 16, 0, 0);
}

// ---- f32 -> bf16 convert (8 elems/thread) ----------------------------------
__global__ __launch_bounds__(256) void cvt_bf16_kernel(const float* __restrict__ in,
    ushort_t* __restrict__ outp, int n8)
{
  const int i = blockIdx.x * 256 + threadIdx.x;
  if (i >= n8) return;
  const float4 a = ((const float4*)in)[2*i];
  const float4 b = ((const float4*)in)[2*i + 1];
  uint4 p;
  p.x = pack2(a.x, a.y); p.y = pack2(a.z, a.w);
  p.z = pack2(b.x, b.y); p.w = pack2(b.z, b.w);
  ((uint4*)outp)[i] = p;
}

// ---- MFMA GEMM, bf16 A and W, global_load_lds staging ----------------------
// C(M,N) = A(M,K) @ W(N,K)^T.  ACT==1: +bias then SiLU. BF16OUT: bf16 else f32.
template<int ACT, int BF16OUT>
__global__ __launch_bounds__(256) void gemm_bf16(const ushort_t* __restrict__ A,
    const ushort_t* __restrict__ W, const float* __restrict__ bias,
    void* __restrict__ Cv, int M, int N, int K)
{
  __shared__ ushort_t As[128*32];
  __shared__ ushort_t Ws[128*32];
  const int tid = threadIdx.x;
  const int bm = blockIdx.y * 128, bn = blockIdx.x * 128;
  const int lane = tid & 63, wave = tid >> 6;
  const int wm = (wave >> 1) * 64, wn = (wave & 1) * 64;
  const int fr = lane & 15, fq = lane >> 4;
  // staging: wave w covers rows w*16..w*16+16 of each 64-row half; lane*16B linear LDS
  const int srow = wave * 16 + (lane >> 2);
  const int scol = (lane & 3) * 8;
  const ushort_t* Ap = A + (size_t)(bm + srow) * K + scol;
  const ushort_t* Wp = W + (size_t)(bn + srow) * K + scol;
  ushort_t* AsD = &As[wave * 512];
  ushort_t* WsD = &Ws[wave * 512];
  floatx4 acc[4][4];
#pragma unroll
  for (int i = 0; i < 4; ++i)
#pragma unroll
    for (int j = 0; j < 4; ++j) acc[i][j] = (floatx4){0.f, 0.f, 0.f, 0.f};

  for (int k0 = 0; k0 < K; k0 += 32) {
    __syncthreads();                       // prev tile reads done
    gload16(Ap + k0, AsD);
    gload16(Ap + (size_t)64 * K + k0, AsD + 64*32);
    gload16(Wp + k0, WsD);
    gload16(Wp + (size_t)64 * K + k0, WsD + 64*32);
    __syncthreads();                       // staging complete (vmcnt drained)
    short8 af[4], bf_[4];
#pragma unroll
    for (int mt = 0; mt < 4; ++mt)
      af[mt] = *(const short8*)&As[(wm + mt*16 + fr)*32 + fq*8];
#pragma unroll
    for (int nt = 0; nt < 4; ++nt)
      bf_[nt] = *(const short8*)&Ws[(wn + nt*16 + fr)*32 + fq*8];
#pragma unroll
    for (int mt = 0; mt < 4; ++mt)
#pragma unroll
      for (int nt = 0; nt < 4; ++nt)
        acc[mt][nt] = __builtin_amdgcn_mfma_f32_16x16x32_bf16(af[mt], bf_[nt], acc[mt][nt], 0, 0, 0);
  }
#pragma unroll
  for (int mt = 0; mt < 4; ++mt) {
#pragma unroll
    for (int reg = 0; reg < 4; ++reg) {
      const int row = bm + wm + mt*16 + fq*4 + reg;
#pragma unroll
      for (int nt = 0; nt < 4; ++nt) {
        const int col = bn + wn + nt*16 + fr;
        float v = acc[mt][nt][reg];
        if (ACT == 1) { v += bias[col]; v = v * sigm(v); }
        if (BF16OUT) ((ushort_t*)Cv)[(size_t)row * N + col] = f2bf(v);
        else         ((float*)Cv)[(size_t)row * N + col] = v;
      }
    }
  }
}

// ---- depthwise causal conv(k=4)+SiLU, bf16 in/out, relayout to (B,H,L,DK) --
__global__ __launch_bounds__(256) void conv_silu_kernel(const ushort_t* __restrict__ xin,
    const float* __restrict__ wc, ushort_t* __restrict__ outp)
{
  const size_t idx = (size_t)blockIdx.x * 256 + threadIdx.x;  // over B*L*D
  const int d = (int)(idx & (DD - 1));
  const int l = (int)((idx >> 10) & (LL - 1));
  const float4 w = *(const float4*)(wc + d * 4);
  const ushort_t* xp = xin + idx;
  float acc = w.w * bf2f(xp[0]);
  if (l >= 1) acc += w.z * bf2f(xp[-DD]);
  if (l >= 2) acc += w.y * bf2f(xp[-2*DD]);
  if (l >= 3) acc += w.x * bf2f(xp[-3*DD]);
  acc = acc * sigm(acc);
  const int b = (int)(idx >> 22);
  const int h = d >> 8, dk = d & 255;
  outp[(((size_t)(b*HH + h))*LL + l)*DKk + dk] = f2bf(acc);
}

// ---- beta / g_s / g_l: 12 length-1024 dots per (b,l), x fp32 ---------------
__global__ __launch_bounds__(256) void small_proj_kernel(const float* __restrict__ x,
   const float* __restrict__ Wb, const float* __restrict__ Wds, const float* __restrict__ bds,
   const float* __restrict__ Wdl, const float* __restrict__ bdl,
   float* __restrict__ beta, float* __restrict__ gs, float* __restrict__ gl)
{
  const int bl = blockIdx.x;
  const int t = threadIdx.x, wave = t >> 6, lane = t & 63;
  __shared__ float res[12];
  const float* xr = x + (size_t)bl * DD + lane * 16;
  const float4 x0 = *(const float4*)(xr);
  const float4 x1 = *(const float4*)(xr + 4);
  const float4 x2 = *(const float4*)(xr + 8);
  const float4 x3 = *(const float4*)(xr + 12);
  for (int rr = 0; rr < 3; ++rr) {
    const int r = wave * 3 + rr;
    const int mat = r >> 2, h = r & 3;
    const float* Wr = (mat == 0 ? Wb : (mat == 1 ? Wds : Wdl)) + (size_t)h * DD + lane * 16;
    const float4 w0 = *(const float4*)(Wr);
    const float4 w1 = *(const float4*)(Wr + 4);
    const float4 w2 = *(const float4*)(Wr + 8);
    const float4 w3 = *(const float4*)(Wr + 12);
    float p = x0.x*w0.x + x0.y*w0.y + x0.z*w0.z + x0.w*w0.w
            + x1.x*w1.x + x1.y*w1.y + x1.z*w1.z + x1.w*w1.w
            + x2.x*w2.x + x2.y*w2.y + x2.z*w2.z + x2.w*w2.w
            + x3.x*w3.x + x3.y*w3.y + x3.z*w3.z + x3.w*w3.w;
#pragma unroll
    for (int o = 1; o < 64; o <<= 1) p += __shfl_xor(p, o);
    if (lane == 0) res[r] = p;
  }
  __syncthreads();
  if (t < 12) {
    const int mat = t >> 2, h = t & 3;
    float v = res[t];
    if (mat == 1) v += bds[h];
    if (mat == 2) v += bdl[h];
    v = sigm(v);
    const int b = bl >> 12, l = bl & (LL - 1);
    const size_t o = ((size_t)(b*HH + h))*LL + l;
    (mat == 0 ? beta : (mat == 1 ? gs : gl))[o] = v;
  }
}

// ---- hierarchical gate: z bf16, 24 length-512 dots + 2-way softmaxes -------
__global__ __launch_bounds__(256) void gate_kernel(const ushort_t* __restrict__ z,
  const float* __restrict__ Wc, const float* __restrict__ bc,
  const float* __restrict__ Wl, const float* __restrict__ bl_,
  const float* __restrict__ Wg, const float* __restrict__ bg,
  const float* __restrict__ ltc, const float* __restrict__ ltf,
  float* __restrict__ wgt)
{
  const int bl = blockIdx.x;
  const int t = threadIdx.x, wave = t >> 6, lane = t & 63;
  __shared__ float res[24];
  const uint4 zv = *(const uint4*)(z + (size_t)bl * HIDD + lane * 8);
  float zf[8]; unpack8(zv, zf);
  for (int rr = 0; rr < 6; ++rr) {
    const int r = wave * 6 + rr;
    const int mat = r >> 3, qi = r & 7;
    const float* Wr = (mat == 0 ? Wc : (mat == 1 ? Wl : Wg)) + (size_t)qi * HIDD + lane * 8;
    const float4 w0 = *(const float4*)(Wr);
    const float4 w1 = *(const float4*)(Wr + 4);
    float p = zf[0]*w0.x + zf[1]*w0.y + zf[2]*w0.z + zf[3]*w0.w
            + zf[4]*w1.x + zf[5]*w1.y + zf[6]*w1.z + zf[7]*w1.w;
#pragma unroll
    for (int o = 1; o < 64; o <<= 1) p += __shfl_xor(p, o);
    if (lane == 0) {
      const float* br = (mat == 0 ? bc : (mat == 1 ? bl_ : bg));
      res[r] = p + br[qi];
    }
  }
  __syncthreads();
  if (t < 4) {
    const float tc = logf(1.f + __expf(ltc[t])) + 1e-4f;
    const float tf = logf(1.f + __expf(ltf[t])) + 1e-4f;
    const float pg0 = sigm((res[2*t]     - res[2*t+1])     / tc);
    const float q0  = sigm((res[8+2*t]   - res[8+2*t+1])   / tf);
    const float r0  = sigm((res[16+2*t]  - res[16+2*t+1])  / tf);
    float* o = wgt + ((size_t)bl * HH + t) * 4;
    o[0] = pg0 * q0;         o[1] = pg0 * (1.f - q0);
    o[2] = (1.f - pg0) * r0; o[3] = (1.f - pg0) * (1.f - r0);
  }
}

// ---- chunk-local prep (bf16 LDS, stride 264): l2norm, attn(hi/lo bf16),
//      triangular solves; emits kT (dk-major) and uT (dv-major) for MFMA scan.
#define QS 264
__global__ __launch_bounds__(256) void prep_kernel(ushort_t* __restrict__ q,
    ushort_t* __restrict__ k, const ushort_t* __restrict__ v,
    const float* __restrict__ beta,
    ushort_t* __restrict__ u, ushort_t* __restrict__ w,
    ushort_t* __restrict__ ah, ushort_t* __restrict__ al)
{
  __shared__ ushort_t qb[32*QS];
  __shared__ ushort_t kb[32*QS];
  __shared__ float Lm[32*32];
  __shared__ float betas[32];
  const int bid = blockIdx.x;
  const int ci = bid & (NC - 1);
  const int bh = bid >> 7;
  const int t = threadIdx.x;
  const size_t base = ((size_t)bh * LL + ci*32) * DKk;
  if (t < 32) betas[t] = beta[(size_t)bh * LL + ci*32 + t];
  for (int i4 = t; i4 < 1024; i4 += 256) {
    const int r = i4 >> 5, e = (i4 & 31) * 8;
    *(uint4*)&qb[r*QS + e] = *(const uint4*)(q + base + r*256 + e);
    *(uint4*)&kb[r*QS + e] = *(const uint4*)(k + base + r*256 + e);
  }
  __syncthreads();
  {
    const int r = t >> 3, g = t & 7;
    float sq = 0.f, sk = 0.f;
    for (int e = g*32; e < g*32 + 32; ++e) {
      const float a = bf2f(qb[r*QS + e]); sq = fmaf(a, a, sq);
      const float c = bf2f(kb[r*QS + e]); sk = fmaf(c, c, sk);
    }
#pragma unroll
    for (int o = 1; o < 8; o <<= 1) { sq += __shfl_xor(sq, o); sk += __shfl_xor(sk, o); }
    const float rq = rsqrtf(sq + 1e-6f), rk = rsqrtf(sk + 1e-6f);
    for (int e = g*32; e < g*32 + 32; ++e) {
      qb[r*QS + e] = f2bf(bf2f(qb[r*QS + e]) * rq);
      kb[r*QS + e] = f2bf(bf2f(kb[r*QS + e]) * rk);
    }
  }
  __syncthreads();
  // write back normalized q (row-major, used as MFMA A-frags in scan)
  for (int i4 = t; i4 < 1024; i4 += 256) {
    const int r = i4 >> 5, e = (i4 & 31) * 8;
    *(uint4*)(q + base + r*256 + e) = *(const uint4*)&qb[r*QS + e];
  }
  // write kT (dk-major: [dk][cr]) into the k slab; thread t = dk
  {
    unsigned int pk[16];
#pragma unroll
    for (int j = 0; j < 16; ++j)
      pk[j] = (unsigned int)kb[(2*j)*QS + t] | ((unsigned int)kb[(2*j+1)*QS + t] << 16);
    uint4* kd = (uint4*)(k + base + (size_t)t*32);
#pragma unroll
    for (int j = 0; j < 4; ++j) kd[j] = ((const uint4*)pk)[j];
  }
  {
    const int j = t & 31, i0 = (t >> 5) * 4;
#pragma unroll
    for (int ii = 0; ii < 4; ++ii) {
      const int i = i0 + ii;
      float dq = 0.f, dk2 = 0.f;
      for (int e = 0; e < 256; ++e) {
        const float kj = bf2f(kb[j*QS + e]);
        dq  = fmaf(bf2f(qb[i*QS + e]), kj, dq);
        dk2 = fmaf(bf2f(kb[i*QS + e]), kj, dk2);
      }
      const float av = (j <= i) ? dq : 0.f;
      const ushort_t hh = f2bf(av);
      const size_t aoff = ((size_t)bh*NC + ci)*1024 + (size_t)i*32 + j;
      ah[aoff] = hh;
      al[aoff] = f2bf(av - bf2f(hh));
      Lm[i*32 + j] = (j < i) ? betas[i] * dk2 : 0.f;
    }
  }
  __syncthreads();
  {
    float cu[32], cw[32];
#pragma unroll
    for (int r = 0; r < 32; ++r) {
      cu[r] = bf2f(v[base + r*256 + t]) * betas[r];
      cw[r] = bf2f(kb[r*QS + t]) * betas[r];
    }
#pragma unroll
    for (int i = 1; i < 32; ++i) {
      float au = cu[i], aw = cw[i];
#pragma unroll
      for (int j = 0; j < i; ++j) {
        const float lm = Lm[i*32 + j];
        au = fmaf(-lm, cu[j], au);
        aw = fmaf(-lm, cw[j], aw);
      }
      cu[i] = au; cw[i] = aw;
    }
    // uT (dv-major: [dv][cr]); thread t = dv -> 64B contiguous
    {
      unsigned int pu[16];
#pragma unroll
      for (int j = 0; j < 16; ++j) pu[j] = pack2(cu[2*j], cu[2*j+1]);
      uint4* ud = (uint4*)(u + base + (size_t)t*32);
#pragma unroll
      for (int j = 0; j < 4; ++j) ud[j] = ((const uint4*)pu)[j];
    }
#pragma unroll
    for (int r = 0; r < 32; ++r) w[base + r*256 + t] = f2bf(cw[r]);
  }
}

// ---- MFMA sequential chunk scan --------------------------------------------
// 128 blocks = 16 bh x 8 dv-slices. 4 waves. S in f32 accumulators, mirrored
// to LDS as bf16 hi+lo. Full operand prefetch one chunk ahead (issued after
// BAR1 so phase2+S-update hides the latency). 2 barriers/chunk.
#define SIDX(ldv,kk) (((ldv)<<8) + ((kk) ^ (((ldv)&7)<<3)))
#define UIDX(ldv,cr) (((ldv)<<5) + ((cr) ^ (((ldv)&3)<<3)))

struct FragsD { short8 w[8]; short8 q[8]; short8 k[4]; short8 ahf, alf; uint2 ut; };

__global__ __launch_bounds__(256, 1) void scan_kernel(
    const ushort_t* __restrict__ qn, const ushort_t* __restrict__ kt,
    const ushort_t* __restrict__ ut, const ushort_t* __restrict__ w,
    const ushort_t* __restrict__ ah, const ushort_t* __restrict__ al,
    float* __restrict__ dout)
{
  __shared__ ushort_t sT[2][32*256];   // [hi/lo][dv][dk], swizzled
  __shared__ ushort_t uhT[2][32*32];   // [hi/lo][dv][cr], swizzled
  const int bid = blockIdx.x;
  const int bh = bid & 15, vs = bid >> 4;  // same bh -> same XCD (bid%8 const)
  const int b = bh >> 2, h = bh & 3;
  const int t = threadIdx.x, lane = t & 63, wave = t >> 6;
  const int fr = lane & 15, fq = lane >> 4;
  const int mtA = wave >> 1, ntA = wave & 1;
  const int ldvA = ntA * 16 + fr;

  for (int i = t; i < 2048; i += 256) ((uint4*)sT)[i] = (uint4){0u,0u,0u,0u};

  const size_t bhL = (size_t)bh * LL;
  const ushort_t* wB  = w  + bhL * DKk;
  const ushort_t* qB  = qn + bhL * DKk;
  const ushort_t* kB  = kt + bhL * DKk;
  const ushort_t* uB  = ut + bhL * DVv;
  const ushort_t* ahB = ah + (size_t)bh * NC * 1024;
  const ushort_t* alB = al + (size_t)bh * NC * 1024;
  float* oB = dout + (size_t)b * LL * DD + h * DVv + vs * 32;

  floatx4 Sacc[8];
#pragma unroll
  for (int i = 0; i < 8; ++i) Sacc[i] = (floatx4){0.f,0.f,0.f,0.f};

  auto loadD = [&](int ci, FragsD& f) {
    const ushort_t* wp = wB + ((size_t)(ci*32 + mtA*16 + fr)) * DKk + fq*8;
    const ushort_t* qp = qB + ((size_t)(ci*32 + mtA*16 + fr)) * DKk + fq*8;
#pragma unroll
    for (int ks = 0; ks < 8; ++ks) {
      f.w[ks] = *(const short8*)(wp + ks*32);
      f.q[ks] = *(const short8*)(qp + ks*32);
    }
    const ushort_t* kp = kB + (size_t)ci*8192 + fq*8;
#pragma unroll
    for (int m = 0; m < 4; ++m)
      f.k[m] = *(const short8*)(kp + (size_t)((wave*4+m)*16 + fr)*32);
    f.ahf = *(const short8*)(ahB + (size_t)ci*1024 + (mtA*16+fr)*32 + fq*8);
    f.alf = *(const short8*)(alB + (size_t)ci*1024 + (mtA*16+fr)*32 + fq*8);
    // u rows for this wave's output tile: cr = mtA*16 + fq*4 + reg
    f.ut = *(const uint2*)(uB + (size_t)ci*8192 + (size_t)(vs*32 + ldvA)*32 + mtA*16 + fq*4);
  };

  FragsD f0, f1;
  loadD(0, f0);
  __syncthreads();   // sT zero-init visible

  auto body = [&](int ci, FragsD& cur, FragsD& nxt) {
    // fused: accA = -u + w@S (-> -uhat), accB = q@S_hi
    floatx4 accA, accB = (floatx4){0.f,0.f,0.f,0.f};
    { float u0,u1,u2,u3; unpack2(cur.ut.x,u0,u1); unpack2(cur.ut.y,u2,u3);
      accA = (floatx4){-u0,-u1,-u2,-u3}; }
#pragma unroll
    for (int ks = 0; ks < 8; ++ks) {
      const short8 sh = *(const short8*)&sT[0][SIDX(ldvA, ks*32 + fq*8)];
      const short8 sl = *(const short8*)&sT[1][SIDX(ldvA, ks*32 + fq*8)];
      accA = __builtin_amdgcn_mfma_f32_16x16x32_bf16(cur.w[ks], sh, accA, 0,0,0);
      accA = __builtin_amdgcn_mfma_f32_16x16x32_bf16(cur.w[ks], sl, accA, 0,0,0);
      accB = __builtin_amdgcn_mfma_f32_16x16x32_bf16(cur.q[ks], sh, accB, 0,0,0);
    }
    // uhat = -accA; exact truncate-split hi/lo -> LDS
    {
      unsigned ph0, pl0, ph1, pl1;
      split2t(-accA[0], -accA[1], ph0, pl0);
      split2t(-accA[2], -accA[3], ph1, pl1);
      const int cr0 = mtA*16 + fq*4;
      uint2 ph; ph.x = ph0; ph.y = ph1;
      uint2 pl; pl.x = pl0; pl.y = pl1;
      *(uint2*)&uhT[0][UIDX(ldvA, cr0)] = ph;
      *(uint2*)&uhT[1][UIDX(ldvA, cr0)] = pl;
    }
    __syncthreads();   // BAR1: uhT ready; all sT reads of this chunk done
    if (ci + 1 < NC) loadD(ci + 1, nxt);   // prefetch hides under phase2+S-upd
    // o = q@S + attn@uhat ; coalesced f32 write
    {
      const short8 uhh = *(const short8*)&uhT[0][UIDX(ldvA, fq*8)];
      const short8 uhl = *(const short8*)&uhT[1][UIDX(ldvA, fq*8)];
      accB = __builtin_amdgcn_mfma_f32_16x16x32_bf16(cur.ahf, uhh, accB, 0,0,0);
      accB = __builtin_amdgcn_mfma_f32_16x16x32_bf16(cur.ahf, uhl, accB, 0,0,0);
      accB = __builtin_amdgcn_mfma_f32_16x16x32_bf16(cur.alf, uhh, accB, 0,0,0);
      float* op = oB + ((size_t)(ci*32 + mtA*16 + fq*4)) * DD + ntA*16 + fr;
#pragma unroll
      for (int r = 0; r < 4; ++r) op[(size_t)r * DD] = accB[r];
    }
    // S += kT @ (uhat_hi + uhat_lo)
#pragma unroll
    for (int nt = 0; nt < 2; ++nt) {
      const int ldv = nt*16 + fr;
      const short8 bhf = *(const short8*)&uhT[0][UIDX(ldv, fq*8)];
      const short8 blf = *(const short8*)&uhT[1][UIDX(ldv, fq*8)];
#pragma unroll
      for (int m = 0; m < 4; ++m) {
        Sacc[m*2+nt] = __builtin_amdgcn_mfma_f32_16x16x32_bf16(cur.k[m], bhf, Sacc[m*2+nt], 0,0,0);
        Sacc[m*2+nt] = __builtin_amdgcn_mfma_f32_16x16x32_bf16(cur.k[m], blf, Sacc[m*2+nt], 0,0,0);
      }
    }
    // mirror S to LDS hi/lo for next chunk
#pragma unroll
    for (int m = 0; m < 4; ++m)
#pragma unroll
      for (int nt = 0; nt < 2; ++nt) {
        const int ldv = nt*16 + fr;
        const int dk0 = (wave*4+m)*16 + fq*4;
        const floatx4 s = Sacc[m*2+nt];
        unsigned ph0, pl0, ph1, pl1;
        split2t(s[0], s[1], ph0, pl0);
        split2t(s[2], s[3], ph1, pl1);
        uint2 ph; ph.x = ph0; ph.y = ph1;
        uint2 pl; pl.x = pl0; pl.y = pl1;
        *(uint2*)&sT[0][SIDX(ldv, dk0)] = ph;
        *(uint2*)&sT[1][SIDX(ldv, dk0)] = pl;
      }
    __syncthreads();   // BAR2: sT ready; uhT readers done
  };

  for (int c2 = 0; c2 < NC; c2 += 2) { body(c2, f0, f1); body(c2+1, f1, f0); }
}

// ---- EMA pass 1: per-segment local scan ------------------------------------
__global__ __launch_bounds__(256) void ema_local_kernel(const ushort_t* __restrict__ v,
  const float* __restrict__ gs, const float* __restrict__ gl,
  ushort_t* __restrict__ es, ushort_t* __restrict__ el,
  float* __restrict__ Bs, float* __restrict__ Bl,
  float* __restrict__ As, float* __restrict__ Al,
  float* __restrict__ PfS, float* __restrict__ PfL)
{
  const int bid = blockIdx.x;
  const int seg = bid & (NSEG - 1), bh = bid >> 6;
  const int b = bh >> 2, h = bh & 3;
  const int dv = threadIdx.x;
  const int l0 = seg * SEG;
  const ushort_t* vp = v + ((size_t)bh*LL + l0) * DVv + dv;
  const float* gsp = gs + (size_t)bh*LL + l0;
  const float* glp = gl + (size_t)bh*LL + l0;
  ushort_t* esp = es + ((size_t)b*LL + l0)*DD + h*DVv + dv;
  ushort_t* elp = el + ((size_t)b*LL + l0)*DD + h*DVv + dv;
  float* pfs = PfS + (size_t)bh*LL + l0;
  float* pfl = PfL + (size_t)bh*LL + l0;
  float s1 = 0.f, s2 = 0.f, p1 = 1.f, p2 = 1.f;
  for (int j = 0; j < SEG; ++j) {
    const float vv = bf2f(vp[(size_t)j * DVv]);
    const float a = gsp[j], g2 = glp[j];
    s1 = fmaf(a,  s1, (1.f - a)  * vv);
    s2 = fmaf(g2, s2, (1.f - g2) * vv);
    p1 *= a; p2 *= g2;
    esp[(size_t)j * DD] = f2bf(s1);
    elp[(size_t)j * DD] = f2bf(s2);
    if (dv == 0) { pfs[j] = p1; pfl[j] = p2; }
  }
  const size_t o = (((size_t)bh*NSEG + seg) << 8) + dv;
  Bs[o] = s1; Bl[o] = s2;
  if (dv == 0) { As[bh*NSEG + seg] = p1; Al[bh*NSEG + seg] = p2; }
}

// ---- EMA pass 2: cross-segment carry (carry INTO each segment) -------------
__global__ __launch_bounds__(256) void ema_carry_kernel(
  const float* __restrict__ Bs, const float* __restrict__ Bl,
  const float* __restrict__ As, const float* __restrict__ Al,
  float* __restrict__ Cs, float* __restrict__ Cl)
{
  const int bh = blockIdx.x;
  const int dv = threadIdx.x;
  __shared__ float Ash[NSEG], Alh[NSEG];
  if (dv < NSEG) { Ash[dv] = As[bh*NSEG + dv]; Alh[dv] = Al[bh*NSEG + dv]; }
  __syncthreads();
  float c1 = 0.f, c2 = 0.f;
  for (int s = 0; s < NSEG; ++s) {
    const size_t o = (((size_t)bh*NSEG + s) << 8) + dv;
    Cs[o] = c1; Cl[o] = c2;
    c1 = fmaf(Ash[s], c1, Bs[o]);
    c2 = fmaf(Alh[s], c2, Bl[o]);
  }
}

// ---- combine + per-head RMSNorm; fuses EMA segment-carry correction --------
__global__ __launch_bounds__(64) void combine_kernel(const ushort_t* __restrict__ v,
  const ushort_t* __restrict__ es, const ushort_t* __restrict__ el,
  const float* __restrict__ dov, const float* __restrict__ wgt,
  const float* __restrict__ onw,
  const float* __restrict__ Cs, const float* __restrict__ Cl,
  const float* __restrict__ PfS, const float* __restrict__ PfL,
  ushort_t* __restrict__ outp)
{
  const int bid = blockIdx.x;
  const int h = bid & 3;
  const size_t bl = (size_t)(bid >> 2);
  const int lane = threadIdx.x;
  const size_t b = bl >> 12;
  const size_t l = bl & (LL - 1);
  const int bh = (int)(b * HH) + h;
  const int seg = (int)(l >> 6);
  const size_t vidx = (((b*HH + h) * (size_t)LL) + l) * DVv + lane*4;
  const size_t didx = bl * DD + h*DVv + lane*4;
  const uint2 vu = *(const uint2*)(v + vidx);
  const uint2 eu = *(const uint2*)(es + didx);
  const uint2 gu = *(const uint2*)(el + didx);
  const float4 d4 = *(const float4*)(dov + didx);
  const float pS = PfS[(size_t)bh*LL + l];
  const float pL = PfL[(size_t)bh*LL + l];
  const float4 cs4 = *(const float4*)(Cs + (((size_t)bh*NSEG + seg) << 8) + lane*4);
  const float4 cl4 = *(const float4*)(Cl + (((size_t)bh*NSEG + seg) << 8) + lane*4);
  float vf[4], ef[4], gf[4];
  unpack2(vu.x, vf[0], vf[1]); unpack2(vu.y, vf[2], vf[3]);
  unpack2(eu.x, ef[0], ef[1]); unpack2(eu.y, ef[2], ef[3]);
  unpack2(gu.x, gf[0], gf[1]); unpack2(gu.y, gf[2], gf[3]);
  ef[0] = fmaf(pS, cs4.x, ef[0]); ef[1] = fmaf(pS, cs4.y, ef[1]);
  ef[2] = fmaf(pS, cs4.z, ef[2]); ef[3] = fmaf(pS, cs4.w, ef[3]);
  gf[0] = fmaf(pL, cl4.x, gf[0]); gf[1] = fmaf(pL, cl4.y, gf[1]);
  gf[2] = fmaf(pL, cl4.z, gf[2]); gf[3] = fmaf(pL, cl4.w, gf[3]);
  const float* wp = wgt + (size_t)bid * 4;
  const float w0 = wp[0], w1 = wp[1], w2 = wp[2], w3 = wp[3];
  float o[4];
  const float df[4] = {d4.x, d4.y, d4.z, d4.w};
  float ss = 0.f;
#pragma unroll
  for (int i = 0; i < 4; ++i) {
    o[i] = w0*vf[i] + w1*ef[i] + w2*df[i] + w3*gf[i];
    ss = fmaf(o[i], o[i], ss);
  }
#pragma unroll
  for (int off = 1; off < 64; off <<= 1) ss += __shfl_xor(ss, off);
  const float sc = rsqrtf(ss * (1.f / DVv) + 1e-5f);
  const float4 nw = *(const float4*)(onw + lane*4);
  uint2 pk;
  pk.x = pack2(o[0]*sc*nw.x, o[1]*sc*nw.y);
  pk.y = pack2(o[2]*sc*nw.z, o[3]*sc*nw.w);
  *(uint2*)(outp + didx) = pk;
}

extern "C" void kernel_launch(void* const* d_in, const int* in_sizes, int n_in,
                              void* d_out, int out_size, void* d_ws, size_t ws_size,
                              hipStream_t stream)
{
  const float* x    = (const float*)d_in[0];
  const float* Wq   = (const float*)d_in[1];
  const float* Wk   = (const float*)d_in[2];
  const float* Wv   = (const float*)d_in[3];
  const float* cqw  = (const float*)d_in[4];
  const float* ckw  = (const float*)d_in[5];
  const float* cvw  = (const float*)d_in[6];
  const float* Wb   = (const float*)d_in[7];
  const float* Wds  = (const float*)d_in[8];
  const float* bds  = (const float*)d_in[9];
  const float* Wdl  = (const float*)d_in[10];
  const float* bdl  = (const float*)d_in[11];
  const float* Wtr  = (const float*)d_in[12];
  const float* btr  = (const float*)d_in[13];
  const float* Wc   = (const float*)d_in[14];
  const float* bc   = (const float*)d_in[15];
  const float* Wl   = (const float*)d_in[16];
  const float* blc  = (const float*)d_in[17];
  const float* Wg   = (const float*)d_in[18];
  const float* bg   = (const float*)d_in[19];
  const float* ltc  = (const float*)d_in[20];
  const float* ltf  = (const float*)d_in[21];
  const float* onw  = (const float*)d_in[22];
  const float* Wo   = (const float*)d_in[23];
  float* outp = (float*)d_out;

  const size_t BLD = (size_t)BB * LL * DD;
  unsigned char* w8 = (unsigned char*)d_ws;
  const size_t SL = BLD * 2;                        // 32 MB bf16 slab
  ushort_t* SA = (ushort_t*)(w8 + 0*SL);   // qraw -> kn -> kT -> opre
  ushort_t* SB = (ushort_t*)(w8 + 1*SL);   // kraw -> vv
  ushort_t* SC = (ushort_t*)(w8 + 2*SL);   // vraw -> uT
  ushort_t* SD = (ushort_t*)(w8 + 3*SL);   // xb -> qn -> el(local)
  ushort_t* SE = (ushort_t*)(w8 + 4*SL);   // w  -> es(local)
  ushort_t* zb   = (ushort_t*)(w8 + 5*SL);
  ushort_t* attn_hi = (ushort_t*)(w8 + 5*SL + BLD);
  ushort_t* attn_lo = attn_hi + (size_t)BB*HH*NC*1024;
  float*    beta = (float*)(attn_hi + 2*(size_t)BB*HH*NC*1024);
  float*    gs   = beta + (size_t)BB*HH*LL;
  float*    gl   = gs   + (size_t)BB*HH*LL;
  float*    wgt  = gl   + (size_t)BB*HH*LL;
  float*    Bs   = wgt  + (size_t)BB*LL*HH*4;
  float*    Bl   = Bs   + (size_t)BB*HH*NSEG*256;
  float*    Cs   = Bl   + (size_t)BB*HH*NSEG*256;
  float*    Cl   = Cs   + (size_t)BB*HH*NSEG*256;
  float*    As   = Cl   + (size_t)BB*HH*NSEG*256;
  float*    Al   = As   + (size_t)BB*HH*NSEG;
  float*    PfS  = Al   + (size_t)BB*HH*NSEG;
  float*    PfL  = PfS  + (size_t)BB*HH*LL;
  ushort_t* Wqb  = (ushort_t*)(PfL + (size_t)BB*HH*LL);
  ushort_t* Wkb  = Wqb + (size_t)DD*DD;
  ushort_t* Wvb  = Wkb + (size_t)DD*DD;
  ushort_t* Wob  = Wvb + (size_t)DD*DD;
  ushort_t* Wtrb = Wob + (size_t)DD*DD;
  ushort_t* xb   = SD;                     // bf16 x, consumed by the 4 x-GEMMs
  float*    dov  = outp;

  const int MBL = BB * LL;  // 16384
  dim3 blk256(256);

  cvt_bf16_kernel<<<dim3((unsigned)(BLD/8/256)), blk256, 0, stream>>>(x, xb, (int)(BLD/8));
  cvt_bf16_kernel<<<dim3(DD*DD/8/256), blk256, 0, stream>>>(Wq, Wqb, DD*DD/8);
  cvt_bf16_kernel<<<dim3(DD*DD/8/256), blk256, 0, stream>>>(Wk, Wkb, DD*DD/8);
  cvt_bf16_kernel<<<dim3(DD*DD/8/256), blk256, 0, stream>>>(Wv, Wvb, DD*DD/8);
  cvt_bf16_kernel<<<dim3(DD*DD/8/256), blk256, 0, stream>>>(Wo, Wob, DD*DD/8);
  cvt_bf16_kernel<<<dim3(HIDD*DD/8/256), blk256, 0, stream>>>(Wtr, Wtrb, HIDD*DD/8);

  gemm_bf16<0,1><<<dim3(DD/128, MBL/128), blk256, 0, stream>>>(xb, Wqb, nullptr, SA, MBL, DD, DD);
  gemm_bf16<0,1><<<dim3(DD/128, MBL/128), blk256, 0, stream>>>(xb, Wkb, nullptr, SB, MBL, DD, DD);
  gemm_bf16<0,1><<<dim3(DD/128, MBL/128), blk256, 0, stream>>>(xb, Wvb, nullptr, SC, MBL, DD, DD);
  gemm_bf16<1,1><<<dim3(HIDD/128, MBL/128), blk256, 0, stream>>>(xb, Wtrb, btr, zb, MBL, HIDD, DD);
  small_proj_kernel<<<dim3(MBL), blk256, 0, stream>>>(x, Wb, Wds, bds, Wdl, bdl, beta, gs, gl);
  gate_kernel<<<dim3(MBL), blk256, 0, stream>>>(zb, Wc, bc, Wl, blc, Wg, bg, ltc, ltf, wgt);
  conv_silu_kernel<<<dim3((unsigned)(BB*LL*DD/256)), blk256, 0, stream>>>(SA, cqw, SD);  // qn=SD
  conv_silu_kernel<<<dim3((unsigned)(BB*LL*DD/256)), blk256, 0, stream>>>(SB, ckw, SA);  // kn=SA
  conv_silu_kernel<<<dim3((unsigned)(BB*LL*DD/256)), blk256, 0, stream>>>(SC, cvw, SB);  // vv=SB
  prep_kernel<<<dim3(BB*HH*NC), blk256, 0, stream>>>(SD, SA, SB, beta, SC, SE, attn_hi, attn_lo); // uT=SC w=SE kT=SA
  scan_kernel<<<dim3(128), blk256, 0, stream>>>(SD, SA, SC, SE, attn_hi, attn_lo, dov);
  ema_local_kernel<<<dim3(BB*HH*NSEG), blk256, 0, stream>>>(SB, gs, gl, SE, SD, Bs, Bl, As, Al, PfS, PfL); // es=SE el=SD
  ema_carry_kernel<<<dim3(BB*HH), blk256, 0, stream>>>(Bs, Bl, As, Al, Cs, Cl);
  combine_kernel<<<dim3(MBL*HH), dim3(64), 0, stream>>>(SB, SE, SD, dov, wgt, onw, Cs, Cl, PfS, PfL, SA); // opre=SA
  gemm_bf16<0,0><<<dim3(DD/128, MBL/128), blk256, 0, stream>>>(SA, Wob, nullptr, outp, MBL, DD, DD);
}